// Round 1
// baseline (4320.229 us; speedup 1.0000x reference)
//
#include <hip/hip_runtime.h>
#include <cstdint>
#include <cstddef>

// ---------------------------------------------------------------------------
// EncoderLayer: B=8 S=1024 D=2048 H=16 Dh=128 FF=8192, fp32 in/out, bf16 compute
// ---------------------------------------------------------------------------

typedef unsigned short u16;
typedef unsigned int   u32;
typedef __attribute__((ext_vector_type(8))) short short8;   // 8 x bf16 (4 VGPR)
typedef __attribute__((ext_vector_type(4))) float f32x4;

constexpr int Bc  = 8;
constexpr int Sc  = 1024;
constexpr int Dc  = 2048;
constexpr int Hc  = 16;
constexpr int Dhc = 128;
constexpr int FFc = 8192;
constexpr int Mc  = Bc * Sc;   // 8192 rows

// ---- bf16 helpers (manual, RNE) -------------------------------------------
__device__ __forceinline__ u16 f2b(float f) {
  u32 u = __builtin_bit_cast(u32, f);
  u += 0x7fffu + ((u >> 16) & 1u);
  return (u16)(u >> 16);
}
__device__ __forceinline__ u32 pack2(float a, float b) {
  return (u32)f2b(a) | ((u32)f2b(b) << 16);
}
__device__ __forceinline__ void unpack8(uint4 u, float* f) {
  u32 w[4] = {u.x, u.y, u.z, u.w};
#pragma unroll
  for (int i = 0; i < 4; ++i) {
    f[2 * i + 0] = __builtin_bit_cast(float, w[i] << 16);
    f[2 * i + 1] = __builtin_bit_cast(float, w[i] & 0xffff0000u);
  }
}

#define GLOAD_LDS16(gp, lp)                                                    \
  __builtin_amdgcn_global_load_lds(                                            \
      (const __attribute__((address_space(1))) void*)(gp),                     \
      (__attribute__((address_space(3))) void*)(lp), 16, 0, 0)

// ---- f32 -> bf16 conversion -----------------------------------------------
__global__ __launch_bounds__(256) void cvt_f32_bf16(const float* __restrict__ in,
                                                    u16* __restrict__ out, int n) {
  int i = (blockIdx.x * 256 + threadIdx.x) << 2;
  if (i >= n) return;
  float4 v = *(const float4*)(in + i);
  ushort4 o;
  o.x = f2b(v.x); o.y = f2b(v.y); o.z = f2b(v.z); o.w = f2b(v.w);
  *(ushort4*)(out + i) = o;
}

// ---- bf16 GEMM: C(M,N) = A(M,K) . Bt(N,K)^T + bias, optional ReLU, bf16 out
// m97 structure: 128x128 tile, BK=32, 4 waves (each 64x64 = 4x4 16x16 frags),
// global_load_lds width-16 staging, linear LDS [128][32].
template <int RELU>
__global__ __launch_bounds__(256) void gemm_bt(const u16* __restrict__ A,
                                               const u16* __restrict__ Bt,
                                               const float* __restrict__ bias,
                                               u16* __restrict__ C,
                                               int M, int N, int K) {
  __shared__ u16 As[128 * 32];   // 8 KB
  __shared__ u16 Bs[128 * 32];   // 8 KB

  const int nbn = N >> 7;
  const int nwg = (M >> 7) * nbn;
  int bid = blockIdx.x;
  // XCD swizzle (nwg is a multiple of 8 for every shape we launch)
  int sw = (bid & 7) * (nwg >> 3) + (bid >> 3);
  const int m0 = (sw / nbn) << 7;
  const int n0 = (sw % nbn) << 7;

  const int tid  = threadIdx.x;
  const int lane = tid & 63;
  const int w    = tid >> 6;        // wave 0..3
  const int wr   = (w >> 1) << 6;   // wave row offset: 0 / 64
  const int wc   = (w & 1) << 6;    // wave col offset: 0 / 64

  const int srow = lane >> 2;         // staging row within 16-row segment
  const int scol = (lane & 3) << 3;   // staging col (8 bf16 = 16B)

  const int rowA = lane & 15;          // fragment row/col within 16-tile
  const int kq   = (lane >> 4) << 3;   // k-chunk: 0,8,16,24

  f32x4 acc[4][4];
#pragma unroll
  for (int m = 0; m < 4; ++m)
#pragma unroll
    for (int n = 0; n < 4; ++n) acc[m][n] = (f32x4){0.f, 0.f, 0.f, 0.f};

  for (int k0 = 0; k0 < K; k0 += 32) {
    __syncthreads();
#pragma unroll
    for (int s2 = 0; s2 < 2; ++s2) {
      int seg = w * 2 + s2;             // 0..7, wave-uniform
      int r   = (seg << 4) + srow;      // tile row 0..127
      GLOAD_LDS16(A  + (size_t)(m0 + r) * K + k0 + scol, &As[seg * 512]);
      GLOAD_LDS16(Bt + (size_t)(n0 + r) * K + k0 + scol, &Bs[seg * 512]);
    }
    __syncthreads();

    short8 af[4], bf[4];
#pragma unroll
    for (int m = 0; m < 4; ++m)
      af[m] = *reinterpret_cast<const short8*>(&As[((wr + m * 16 + rowA) << 5) + kq]);
#pragma unroll
    for (int n = 0; n < 4; ++n)
      bf[n] = *reinterpret_cast<const short8*>(&Bs[((wc + n * 16 + rowA) << 5) + kq]);

#pragma unroll
    for (int m = 0; m < 4; ++m)
#pragma unroll
      for (int n = 0; n < 4; ++n)
        acc[m][n] = __builtin_amdgcn_mfma_f32_16x16x32_bf16(af[m], bf[n], acc[m][n], 0, 0, 0);
  }

  // epilogue: C/D layout col=lane&15, row=(lane>>4)*4+j   [m89/m91 verified]
  const int ci = lane & 15;
  const int ri = (lane >> 4) << 2;
#pragma unroll
  for (int n = 0; n < 4; ++n) {
    int col  = n0 + wc + n * 16 + ci;
    float bv = bias[col];
#pragma unroll
    for (int m = 0; m < 4; ++m) {
      int row0 = m0 + wr + m * 16 + ri;
#pragma unroll
      for (int j = 0; j < 4; ++j) {
        float v = acc[m][n][j] + bv;
        if (RELU) v = fmaxf(v, 0.f);
        C[(size_t)(row0 + j) * N + col] = f2b(v);
      }
    }
  }
}

// ---- flash-style attention, fp32 math on bf16 inputs ----------------------
// grid: B*H*(S/32); block 256. Each block: one (b,h) and 32 q-rows.
__global__ __launch_bounds__(256) void attn_kernel(const u16* __restrict__ qb,
                                                   const u16* __restrict__ kb,
                                                   const u16* __restrict__ vb,
                                                   const int* __restrict__ mask,
                                                   u16* __restrict__ ob) {
  const int S = Sc, MD = Dc;
  int bid = blockIdx.x;
  int qt = bid & 31;            // S/32 = 32 q-tiles
  int h  = (bid >> 5) & (Hc - 1);
  int b  = bid >> 9;
  int q0 = qt * 32;
  int tid = threadIdx.x;

  __shared__ float Qs[32][129];   // +1 pad: conflict-free row-spread reads
  __shared__ float Ks[32][129];
  __shared__ float Vs[32][129];
  __shared__ float Ps[32][33];
  __shared__ float arow_s[32], lrow_s[32];

  const size_t base = ((size_t)b * S) * MD + (size_t)h * Dhc;

  for (int it = tid; it < 512; it += 256) {
    int r = it >> 4, c = (it & 15) << 3;
    uint4 u = *(const uint4*)(qb + base + (size_t)(q0 + r) * MD + c);
    unpack8(u, &Qs[r][c]);
  }

  float O[16];
#pragma unroll
  for (int i = 0; i < 16; ++i) O[i] = 0.f;
  float m_r = -INFINITY, l_r = 0.f;   // live only in tid<32

  const int qi    = tid >> 3;
  const int kj0   = (tid & 7) << 2;
  const int r_own = tid >> 3;
  const int cl    = tid & 7;          // owns cols cl + 8*i (bank-spread)

  for (int kt = 0; kt < S / 32; ++kt) {
    int k0 = kt * 32;
    __syncthreads();
    for (int it = tid; it < 512; it += 256) {
      int r = it >> 4, c = (it & 15) << 3;
      size_t off = base + (size_t)(k0 + r) * MD + c;
      uint4 uk = *(const uint4*)(kb + off);
      uint4 uv = *(const uint4*)(vb + off);
      unpack8(uk, &Ks[r][c]);
      unpack8(uv, &Vs[r][c]);
    }
    __syncthreads();

    float s0 = 0, s1 = 0, s2 = 0, s3 = 0;
#pragma unroll 4
    for (int d = 0; d < 128; ++d) {
      float qv = Qs[qi][d];
      s0 = fmaf(qv, Ks[kj0 + 0][d], s0);
      s1 = fmaf(qv, Ks[kj0 + 1][d], s1);
      s2 = fmaf(qv, Ks[kj0 + 2][d], s2);
      s3 = fmaf(qv, Ks[kj0 + 3][d], s3);
    }
    const float scale = 0.08838834764831845f;   // 1/sqrt(128)
    float sv[4] = {s0, s1, s2, s3};
#pragma unroll
    for (int j = 0; j < 4; ++j) {
      int kg = k0 + kj0 + j;
      float xv = sv[j] * scale;
      if (mask[(size_t)(q0 + qi) * S + kg] == 0) xv = -1e9f;
      Ps[qi][kj0 + j] = xv;
    }
    __syncthreads();

    if (tid < 32) {
      float mx = m_r;
#pragma unroll 8
      for (int j = 0; j < 32; ++j) mx = fmaxf(mx, Ps[tid][j]);
      float alpha = __expf(m_r - mx);   // first tile: exp(-inf)=0
      float sum = 0.f;
#pragma unroll 8
      for (int j = 0; j < 32; ++j) {
        float p = __expf(Ps[tid][j] - mx);
        Ps[tid][j] = p;
        sum += p;
      }
      l_r = l_r * alpha + sum;
      m_r = mx;
      arow_s[tid] = alpha;
      lrow_s[tid] = l_r;
    }
    __syncthreads();

    float alpha = arow_s[r_own];
#pragma unroll
    for (int i = 0; i < 16; ++i) O[i] *= alpha;
    for (int j = 0; j < 32; ++j) {
      float p = Ps[r_own][j];
#pragma unroll
      for (int i = 0; i < 16; ++i)
        O[i] = fmaf(p, Vs[j][cl + (i << 3)], O[i]);
    }
  }

  float inv = 1.f / lrow_s[r_own];
  u16* op = ob + base + (size_t)(q0 + r_own) * MD;
#pragma unroll
  for (int i = 0; i < 16; ++i) op[cl + (i << 3)] = f2b(O[i] * inv);
}

// ---- fused residual + LayerNorm -------------------------------------------
// a: bf16 main input; resid: fp32 (RES_BF16=0) or bf16 (RES_BF16=1);
// out: bf16 (OUT_BF16=1) or fp32. One block per row, D=2048, 8 elems/thread.
template <int RES_BF16, int OUT_BF16>
__global__ __launch_bounds__(256) void ln_kernel(const u16* __restrict__ a,
                                                 const void* __restrict__ resid,
                                                 const float* __restrict__ g,
                                                 const float* __restrict__ be,
                                                 void* __restrict__ out) {
  int row = blockIdx.x;
  int tid = threadIdx.x;
  int c0  = tid << 3;

  float v[8], vr[8];
  uint4 ua = *(const uint4*)(a + (size_t)row * Dc + c0);
  unpack8(ua, v);
  if (RES_BF16) {
    uint4 ur = *(const uint4*)((const u16*)resid + (size_t)row * Dc + c0);
    unpack8(ur, vr);
  } else {
    const float* rp = (const float*)resid + (size_t)row * Dc + c0;
    float4 f0 = *(const float4*)rp;
    float4 f1 = *(const float4*)(rp + 4);
    vr[0] = f0.x; vr[1] = f0.y; vr[2] = f0.z; vr[3] = f0.w;
    vr[4] = f1.x; vr[5] = f1.y; vr[6] = f1.z; vr[7] = f1.w;
  }

  float s = 0.f, ss = 0.f;
#pragma unroll
  for (int j = 0; j < 8; ++j) {
    v[j] += vr[j];
    s += v[j];
    ss += v[j] * v[j];
  }
#pragma unroll
  for (int off = 32; off; off >>= 1) {
    s  += __shfl_down(s, off);
    ss += __shfl_down(ss, off);
  }
  __shared__ float rs[4], rss[4], stat[2];
  if ((tid & 63) == 0) { rs[tid >> 6] = s; rss[tid >> 6] = ss; }
  __syncthreads();
  if (tid == 0) {
    float t  = rs[0] + rs[1] + rs[2] + rs[3];
    float tt = rss[0] + rss[1] + rss[2] + rss[3];
    float mean = t * (1.f / Dc);
    float var  = tt * (1.f / Dc) - mean * mean;
    stat[0] = mean;
    stat[1] = rsqrtf(var + 1e-5f);
  }
  __syncthreads();
  float mean = stat[0], rstd = stat[1];

  float y[8];
#pragma unroll
  for (int j = 0; j < 8; ++j) y[j] = (v[j] - mean) * rstd * g[c0 + j] + be[c0 + j];

  if (OUT_BF16) {
    uint4 o;
    o.x = pack2(y[0], y[1]); o.y = pack2(y[2], y[3]);
    o.z = pack2(y[4], y[5]); o.w = pack2(y[6], y[7]);
    *(uint4*)((u16*)out + (size_t)row * Dc + c0) = o;
  } else {
    float* op = (float*)out + (size_t)row * Dc + c0;
    *(float4*)op       = (float4){y[0], y[1], y[2], y[3]};
    *(float4*)(op + 4) = (float4){y[4], y[5], y[6], y[7]};
  }
}

// ---------------------------------------------------------------------------
extern "C" void kernel_launch(void* const* d_in, const int* in_sizes, int n_in,
                              void* d_out, int out_size, void* d_ws, size_t ws_size,
                              hipStream_t stream) {
  (void)in_sizes; (void)n_in; (void)out_size; (void)ws_size;

  const float* x   = (const float*)d_in[0];
  const int*   mk  = (const int*)d_in[1];
  const float* Wq  = (const float*)d_in[2];
  const float* bq  = (const float*)d_in[3];
  const float* Wk  = (const float*)d_in[4];
  const float* bk  = (const float*)d_in[5];
  const float* Wv  = (const float*)d_in[6];
  const float* bv  = (const float*)d_in[7];
  const float* Wo  = (const float*)d_in[8];
  const float* bo  = (const float*)d_in[9];
  const float* W1  = (const float*)d_in[10];
  const float* b1  = (const float*)d_in[11];
  const float* W2  = (const float*)d_in[12];
  const float* b2  = (const float*)d_in[13];
  const float* g1  = (const float*)d_in[14];
  const float* be1 = (const float*)d_in[15];
  const float* g2  = (const float*)d_in[16];
  const float* be2 = (const float*)d_in[17];
  float* outp = (float*)d_out;

  // workspace arena: 8 regions x 32MB (bf16, 16777216 elems each). Peak 256MB.
  const size_t R = 16777216;
  u16* xb  = (u16*)d_ws;       // [0] x in bf16
  u16* wb  = xb + R;           // [1] weight staging (reused per GEMM)
  u16* qb  = wb + R;           // [2] q
  u16* kb  = qb + R;           // [3] k
  u16* vb  = kb + R;           // [4] v
  u16* ao  = vb + R;           // [5] attention out (pre-Wo)
  u16* ap  = qb;               // [2] attn projection (q dead)
  u16* x1  = kb;               // [3] post-LN1 (k dead)
  u16* hb  = vb;               // [4..7] FFN hidden 8192x8192 (v, ao dead)
  u16* ffn = xb;               // [0] FFN out (xb dead)

  auto cvt = [&](const float* src, u16* dst, int n) {
    cvt_f32_bf16<<<dim3((n + 1023) / 1024), dim3(256), 0, stream>>>(src, dst, n);
  };

  cvt(x, xb, Mc * Dc);

  // QKV projections
  cvt(Wq, wb, Dc * Dc);
  gemm_bt<0><<<dim3(64 * 16), dim3(256), 0, stream>>>(xb, wb, bq, qb, Mc, Dc, Dc);
  cvt(Wk, wb, Dc * Dc);
  gemm_bt<0><<<dim3(64 * 16), dim3(256), 0, stream>>>(xb, wb, bk, kb, Mc, Dc, Dc);
  cvt(Wv, wb, Dc * Dc);
  gemm_bt<0><<<dim3(64 * 16), dim3(256), 0, stream>>>(xb, wb, bv, vb, Mc, Dc, Dc);

  // attention
  attn_kernel<<<dim3(Bc * Hc * (Sc / 32)), dim3(256), 0, stream>>>(qb, kb, vb, mk, ao);

  // output projection + LN1
  cvt(Wo, wb, Dc * Dc);
  gemm_bt<0><<<dim3(64 * 16), dim3(256), 0, stream>>>(ao, wb, bo, ap, Mc, Dc, Dc);
  ln_kernel<0, 1><<<dim3(Mc), dim3(256), 0, stream>>>(ap, x, g1, be1, x1);

  // FFN
  cvt(W1, wb, FFc * Dc);
  gemm_bt<1><<<dim3(64 * 64), dim3(256), 0, stream>>>(x1, wb, b1, hb, Mc, FFc, Dc);
  cvt(W2, wb, Dc * FFc);
  gemm_bt<0><<<dim3(64 * 16), dim3(256), 0, stream>>>(hb, wb, b2, ffn, Mc, Dc, FFc);
  ln_kernel<1, 0><<<dim3(Mc), dim3(256), 0, stream>>>(ffn, x1, g2, be2, outp);
}

// Round 3
// 1543.577 us; speedup vs baseline: 2.7988x; 2.7988x over previous
//
#include <hip/hip_runtime.h>
#include <cstdint>
#include <cstddef>

// ---------------------------------------------------------------------------
// EncoderLayer: B=8 S=1024 D=2048 H=16 Dh=128 FF=8192, fp32 in/out, bf16 compute
// ---------------------------------------------------------------------------

typedef unsigned short u16;
typedef unsigned int   u32;
typedef unsigned long long u64;
typedef __attribute__((ext_vector_type(8))) short short8;   // 8 x bf16 (4 VGPR)
typedef __attribute__((ext_vector_type(4))) float f32x4;

constexpr int Bc  = 8;
constexpr int Sc  = 1024;
constexpr int Dc  = 2048;
constexpr int Hc  = 16;
constexpr int Dhc = 128;
constexpr int FFc = 8192;
constexpr int Mc  = Bc * Sc;   // 8192 rows

// ---- bf16 helpers (manual, RNE) -------------------------------------------
__device__ __forceinline__ u16 f2b(float f) {
  u32 u = __builtin_bit_cast(u32, f);
  u += 0x7fffu + ((u >> 16) & 1u);
  return (u16)(u >> 16);
}
__device__ __forceinline__ u32 pack2(float a, float b) {
  return (u32)f2b(a) | ((u32)f2b(b) << 16);
}
__device__ __forceinline__ void unpack8(uint4 u, float* f) {
  u32 w[4] = {u.x, u.y, u.z, u.w};
#pragma unroll
  for (int i = 0; i < 4; ++i) {
    f[2 * i + 0] = __builtin_bit_cast(float, w[i] << 16);
    f[2 * i + 1] = __builtin_bit_cast(float, w[i] & 0xffff0000u);
  }
}

#define GLOAD_LDS16(gp, lp)                                                    \
  __builtin_amdgcn_global_load_lds(                                            \
      (const __attribute__((address_space(1))) void*)(gp),                     \
      (__attribute__((address_space(3))) void*)(lp), 16, 0, 0)

// ---- f32 -> bf16 conversion -----------------------------------------------
__global__ __launch_bounds__(256) void cvt_f32_bf16(const float* __restrict__ in,
                                                    u16* __restrict__ out, int n) {
  int i = (blockIdx.x * 256 + threadIdx.x) << 2;
  if (i >= n) return;
  float4 v = *(const float4*)(in + i);
  ushort4 o;
  o.x = f2b(v.x); o.y = f2b(v.y); o.z = f2b(v.z); o.w = f2b(v.w);
  *(ushort4*)(out + i) = o;
}

// ---- mask -> bitmask: mb[s][w] bit i = (mask[s][w*64+i] != 0) --------------
__global__ __launch_bounds__(256) void mask_bits(const int* __restrict__ mask,
                                                 u64* __restrict__ mb) {
  int t = blockIdx.x * 256 + threadIdx.x;   // 16384 = 1024 * 16
  int r = t >> 4, wd = t & 15;
  const int* p = mask + (size_t)r * Sc + wd * 64;
  u64 bits = 0;
#pragma unroll 16
  for (int i = 0; i < 64; i += 4) {
    int4 q = *(const int4*)(p + i);
    bits |= (u64)(q.x != 0) << (i + 0);
    bits |= (u64)(q.y != 0) << (i + 1);
    bits |= (u64)(q.z != 0) << (i + 2);
    bits |= (u64)(q.w != 0) << (i + 3);
  }
  mb[t] = bits;
}

// ---- bf16 GEMM: C(M,N) = A(M,K) . Bt(N,K)^T + bias -------------------------
// MODE 0: bf16 out. MODE 1: ReLU + bf16 out.
// MODE 2: write transposed attention layout vt[b][h][d][s] (for the V proj).
template <int MODE>
__global__ __launch_bounds__(256) void gemm_bt(const u16* __restrict__ A,
                                               const u16* __restrict__ Bt,
                                               const float* __restrict__ bias,
                                               u16* __restrict__ C,
                                               int M, int N, int K) {
  __shared__ u16 As[128 * 32];   // 8 KB
  __shared__ u16 Bs[128 * 32];   // 8 KB

  const int nbn = N >> 7;
  const int nwg = (M >> 7) * nbn;
  int bid = blockIdx.x;
  int sw = (bid & 7) * (nwg >> 3) + (bid >> 3);   // nwg always multiple of 8
  const int m0 = (sw / nbn) << 7;
  const int n0 = (sw % nbn) << 7;

  const int tid  = threadIdx.x;
  const int lane = tid & 63;
  const int w    = tid >> 6;        // wave 0..3
  const int wr   = (w >> 1) << 6;   // wave row offset: 0 / 64
  const int wc   = (w & 1) << 6;    // wave col offset: 0 / 64

  const int srow = lane >> 2;         // staging row within 16-row segment
  const int scol = (lane & 3) << 3;   // staging col (8 bf16 = 16B)

  const int rowA = lane & 15;          // fragment row/col within 16-tile
  const int kq   = (lane >> 4) << 3;   // k-chunk: 0,8,16,24

  f32x4 acc[4][4];
#pragma unroll
  for (int m = 0; m < 4; ++m)
#pragma unroll
    for (int n = 0; n < 4; ++n) acc[m][n] = (f32x4){0.f, 0.f, 0.f, 0.f};

  for (int k0 = 0; k0 < K; k0 += 32) {
    __syncthreads();
#pragma unroll
    for (int s2 = 0; s2 < 2; ++s2) {
      int seg = w * 2 + s2;             // 0..7, wave-uniform
      int r   = (seg << 4) + srow;      // tile row 0..127
      GLOAD_LDS16(A  + (size_t)(m0 + r) * K + k0 + scol, &As[seg * 512]);
      GLOAD_LDS16(Bt + (size_t)(n0 + r) * K + k0 + scol, &Bs[seg * 512]);
    }
    __syncthreads();

    short8 af[4], bf[4];
#pragma unroll
    for (int m = 0; m < 4; ++m)
      af[m] = *reinterpret_cast<const short8*>(&As[((wr + m * 16 + rowA) << 5) + kq]);
#pragma unroll
    for (int n = 0; n < 4; ++n)
      bf[n] = *reinterpret_cast<const short8*>(&Bs[((wc + n * 16 + rowA) << 5) + kq]);

#pragma unroll
    for (int m = 0; m < 4; ++m)
#pragma unroll
      for (int n = 0; n < 4; ++n)
        acc[m][n] = __builtin_amdgcn_mfma_f32_16x16x32_bf16(af[m], bf[n], acc[m][n], 0, 0, 0);
  }

  // epilogue: C/D layout col=lane&15, row=(lane>>4)*4+j
  const int ci = lane & 15;
  const int ri = (lane >> 4) << 2;
#pragma unroll
  for (int n = 0; n < 4; ++n) {
    int col  = n0 + wc + n * 16 + ci;
    float bv = bias[col];
#pragma unroll
    for (int m = 0; m < 4; ++m) {
      int row0 = m0 + wr + m * 16 + ri;
      if (MODE == 2) {
        // vt[b][h][d][s]: 4 consecutive s per lane -> ushort4 store
        ushort4 pk;
        pk.x = f2b(acc[m][n][0] + bv);
        pk.y = f2b(acc[m][n][1] + bv);
        pk.z = f2b(acc[m][n][2] + bv);
        pk.w = f2b(acc[m][n][3] + bv);
        size_t addr = ((size_t)((row0 >> 10) * Hc + (col >> 7)) * 128 + (col & 127)) * 1024
                      + (row0 & 1023);
        *(ushort4*)(C + addr) = pk;
      } else {
#pragma unroll
        for (int j = 0; j < 4; ++j) {
          float v = acc[m][n][j] + bv;
          if (MODE == 1) v = fmaxf(v, 0.f);
          C[(size_t)(row0 + j) * N + col] = f2b(v);
        }
      }
    }
  }
}

// ---- MFMA flash attention --------------------------------------------------
// Block: 256 thr (4 waves). QBLK=128 (wave owns 32 q-rows), KVBLK=64.
// Grid: B*H*(S/128) = 1024. Q in regs; K and V^T staged in swizzled LDS via
// pre-swizzled global_load_lds; P bounced through per-wave swizzled LDS.
__global__ __launch_bounds__(256, 2) void attn_mfma(
    const u16* __restrict__ qb,   // [B*S][D]
    const u16* __restrict__ kb,   // [B*S][D]
    const u16* __restrict__ vt,   // [B*H][128][1024]   (d, s)
    const u64* __restrict__ mb,   // [S][16] bitmask
    u16* __restrict__ ob)         // [B*S][D]
{
  __shared__ u16 Ks[64 * 128];    // 16 KB, byte ^= ((krow&7)<<4), row stride 256B
  __shared__ u16 Vts[128 * 64];   // 16 KB, byte ^= ((drow&7)<<4), row stride 128B
  __shared__ u16 Ps[4][32 * 64];  // 16 KB, per-wave P, row stride 128B

  const int bid = blockIdx.x;
  const int l   = (bid & 7) * 128 + (bid >> 3);   // XCD-chunked: same (b,h) together
  const int qt  = l & 7;
  const int bh  = l >> 3;          // 0..127
  const int h   = bh & (Hc - 1);
  const int b   = bh >> 4;
  const int q0  = qt * 128;

  const int tid  = threadIdx.x;
  const int lane = tid & 63;
  const int w    = tid >> 6;
  const int rowA = lane & 15;
  const int g4   = lane >> 4;          // 0..3
  const int kq16 = g4 << 3;            // 0,8,16,24 (elems)
  const int ri   = g4 << 2;            // acc row base

  const size_t tokbase = (size_t)b * Sc * Dc + (size_t)h * Dhc;
  const size_t vtbase  = (size_t)bh * 128 * 1024;
  const int qwbase = q0 + w * 32;

  // Q fragments in registers
  short8 qf[2][4];
#pragma unroll
  for (int m = 0; m < 2; ++m)
#pragma unroll
    for (int kk = 0; kk < 4; ++kk)
      qf[m][kk] = *reinterpret_cast<const short8*>(
          qb + tokbase + (size_t)(qwbase + m * 16 + rowA) * Dc + kk * 32 + kq16);

  f32x4 O[2][8];
#pragma unroll
  for (int m = 0; m < 2; ++m)
#pragma unroll
    for (int n = 0; n < 8; ++n) O[m][n] = (f32x4){0.f, 0.f, 0.f, 0.f};
  float mrow[2][4], lrow[2][4];
#pragma unroll
  for (int m = 0; m < 2; ++m)
#pragma unroll
    for (int j = 0; j < 4; ++j) { mrow[m][j] = -INFINITY; lrow[m][j] = 0.f; }

  const float scale = 0.08838834764831845f;   // 1/sqrt(128)

  for (int kt = 0; kt < Sc / 64; ++kt) {
    const int k0 = kt * 64;
    __syncthreads();
    // ---- stage K tile (64x128), pre-swizzled source so reads can XOR ------
#pragma unroll
    for (int i = 0; i < 4; ++i) {
      int chunk = w * 4 + i;                      // wave-uniform
      int gb = (chunk * 64 + lane) * 16;
      int L  = gb ^ (((gb >> 8) & 7) << 4);
      int row = L >> 8, ce = (L & 255) >> 1;
      GLOAD_LDS16(kb + tokbase + (size_t)(k0 + row) * Dc + ce, &Ks[chunk * 512]);
    }
    // ---- stage V^T tile (128x64) ------------------------------------------
#pragma unroll
    for (int i = 0; i < 4; ++i) {
      int chunk = w * 4 + i;
      int gb = (chunk * 64 + lane) * 16;
      int L  = gb ^ (((gb >> 7) & 7) << 4);
      int row = L >> 7, ce = (L & 127) >> 1;
      GLOAD_LDS16(vt + vtbase + (size_t)row * 1024 + k0 + ce, &Vts[chunk * 512]);
    }
    __syncthreads();

    // ---- QK^T: s[m][n] over 4 k-chunks ------------------------------------
    f32x4 s[2][4];
#pragma unroll
    for (int m = 0; m < 2; ++m)
#pragma unroll
      for (int n = 0; n < 4; ++n) s[m][n] = (f32x4){0.f, 0.f, 0.f, 0.f};
#pragma unroll
    for (int kk = 0; kk < 4; ++kk) {
      short8 bfk[4];
#pragma unroll
      for (int n = 0; n < 4; ++n) {
        int krow = n * 16 + rowA;
        int by = (krow * 256 + kk * 64 + (g4 << 4)) ^ ((krow & 7) << 4);
        bfk[n] = *reinterpret_cast<const short8*>((const char*)Ks + by);
      }
#pragma unroll
      for (int m = 0; m < 2; ++m)
#pragma unroll
        for (int n = 0; n < 4; ++n)
          s[m][n] = __builtin_amdgcn_mfma_f32_16x16x32_bf16(qf[m][kk], bfk[n], s[m][n], 0, 0, 0);
    }

    // ---- mask + online softmax --------------------------------------------
    float alpha[2][4];
#pragma unroll
    for (int m = 0; m < 2; ++m) {
      u64 wb_[4];
#pragma unroll
      for (int j = 0; j < 4; ++j)
        wb_[j] = mb[(size_t)(qwbase + m * 16 + ri + j) * 16 + kt];
#pragma unroll
      for (int j = 0; j < 4; ++j) {
        float pv[4];
        float mx = -3.0e38f;
#pragma unroll
        for (int n = 0; n < 4; ++n) {
          float x = s[m][n][j] * scale;
          if (!((wb_[j] >> (n * 16 + rowA)) & 1)) x = -1e9f;
          pv[n] = x;
          mx = fmaxf(mx, x);
        }
        mx = fmaxf(mx, __shfl_xor(mx, 1));
        mx = fmaxf(mx, __shfl_xor(mx, 2));
        mx = fmaxf(mx, __shfl_xor(mx, 4));
        mx = fmaxf(mx, __shfl_xor(mx, 8));
        float mnew = fmaxf(mrow[m][j], mx);
        float a = __expf(mrow[m][j] - mnew);
        mrow[m][j] = mnew;
        alpha[m][j] = a;
        float rs = 0.f;
#pragma unroll
        for (int n = 0; n < 4; ++n) {
          float p = __expf(pv[n] - mnew);
          pv[n] = p;
          rs += p;
        }
        rs += __shfl_xor(rs, 1);
        rs += __shfl_xor(rs, 2);
        rs += __shfl_xor(rs, 4);
        rs += __shfl_xor(rs, 8);
        lrow[m][j] = lrow[m][j] * a + rs;
        int prow = m * 16 + ri + j;
#pragma unroll
        for (int n = 0; n < 4; ++n) {
          int by = (prow * 128 + 2 * (n * 16 + rowA)) ^ ((prow & 7) << 4);
          *(u16*)((char*)Ps[w] + by) = f2b(pv[n]);
        }
      }
    }
    asm volatile("s_waitcnt lgkmcnt(0)" ::: "memory");

    // ---- rescale O, then PV ------------------------------------------------
#pragma unroll
    for (int m = 0; m < 2; ++m)
#pragma unroll
      for (int n = 0; n < 8; ++n)
#pragma unroll
        for (int j = 0; j < 4; ++j) O[m][n][j] *= alpha[m][j];

    short8 pa[2][2];
#pragma unroll
    for (int m = 0; m < 2; ++m)
#pragma unroll
      for (int kk = 0; kk < 2; ++kk) {
        int prow = m * 16 + rowA;
        int by = (prow * 128 + kk * 64 + (g4 << 4)) ^ ((prow & 7) << 4);
        pa[m][kk] = *reinterpret_cast<const short8*>((const char*)Ps[w] + by);
      }
#pragma unroll
    for (int kk = 0; kk < 2; ++kk)
#pragma unroll
      for (int n = 0; n < 8; ++n) {
        int drow = n * 16 + rowA;
        int by = (drow * 128 + kk * 64 + (g4 << 4)) ^ ((drow & 7) << 4);
        short8 bfv = *reinterpret_cast<const short8*>((const char*)Vts + by);
#pragma unroll
        for (int m = 0; m < 2; ++m)
          O[m][n] = __builtin_amdgcn_mfma_f32_16x16x32_bf16(pa[m][kk], bfv, O[m][n], 0, 0, 0);
      }
  }

  // ---- normalize + write --------------------------------------------------
  float inv[2][4];
#pragma unroll
  for (int m = 0; m < 2; ++m)
#pragma unroll
    for (int j = 0; j < 4; ++j) inv[m][j] = 1.f / lrow[m][j];
#pragma unroll
  for (int m = 0; m < 2; ++m)
#pragma unroll
    for (int n = 0; n < 8; ++n) {
      int dcol = n * 16 + rowA;
#pragma unroll
      for (int j = 0; j < 4; ++j) {
        int qg = qwbase + m * 16 + ri + j;
        ob[tokbase + (size_t)qg * Dc + dcol] = f2b(O[m][n][j] * inv[m][j]);
      }
    }
}

// ---- fused residual + LayerNorm -------------------------------------------
template <int RES_BF16, int OUT_BF16>
__global__ __launch_bounds__(256) void ln_kernel(const u16* __restrict__ a,
                                                 const void* __restrict__ resid,
                                                 const float* __restrict__ g,
                                                 const float* __restrict__ be,
                                                 void* __restrict__ out) {
  int row = blockIdx.x;
  int tid = threadIdx.x;
  int c0  = tid << 3;

  float v[8], vr[8];
  uint4 ua = *(const uint4*)(a + (size_t)row * Dc + c0);
  unpack8(ua, v);
  if (RES_BF16) {
    uint4 ur = *(const uint4*)((const u16*)resid + (size_t)row * Dc + c0);
    unpack8(ur, vr);
  } else {
    const float* rp = (const float*)resid + (size_t)row * Dc + c0;
    float4 f0 = *(const float4*)rp;
    float4 f1 = *(const float4*)(rp + 4);
    vr[0] = f0.x; vr[1] = f0.y; vr[2] = f0.z; vr[3] = f0.w;
    vr[4] = f1.x; vr[5] = f1.y; vr[6] = f1.z; vr[7] = f1.w;
  }

  float s = 0.f, ss = 0.f;
#pragma unroll
  for (int j = 0; j < 8; ++j) {
    v[j] += vr[j];
    s += v[j];
    ss += v[j] * v[j];
  }
#pragma unroll
  for (int off = 32; off; off >>= 1) {
    s  += __shfl_down(s, off);
    ss += __shfl_down(ss, off);
  }
  __shared__ float rs[4], rss[4], stat[2];
  if ((tid & 63) == 0) { rs[tid >> 6] = s; rss[tid >> 6] = ss; }
  __syncthreads();
  if (tid == 0) {
    float t  = rs[0] + rs[1] + rs[2] + rs[3];
    float tt = rss[0] + rss[1] + rss[2] + rss[3];
    float mean = t * (1.f / Dc);
    float var  = tt * (1.f / Dc) - mean * mean;
    stat[0] = mean;
    stat[1] = rsqrtf(var + 1e-5f);
  }
  __syncthreads();
  float mean = stat[0], rstd = stat[1];

  float y[8];
#pragma unroll
  for (int j = 0; j < 8; ++j) y[j] = (v[j] - mean) * rstd * g[c0 + j] + be[c0 + j];

  if (OUT_BF16) {
    uint4 o;
    o.x = pack2(y[0], y[1]); o.y = pack2(y[2], y[3]);
    o.z = pack2(y[4], y[5]); o.w = pack2(y[6], y[7]);
    *(uint4*)((u16*)out + (size_t)row * Dc + c0) = o;
  } else {
    float* op = (float*)out + (size_t)row * Dc + c0;
    *(float4*)op       = (float4){y[0], y[1], y[2], y[3]};
    *(float4*)(op + 4) = (float4){y[4], y[5], y[6], y[7]};
  }
}

// ---------------------------------------------------------------------------
extern "C" void kernel_launch(void* const* d_in, const int* in_sizes, int n_in,
                              void* d_out, int out_size, void* d_ws, size_t ws_size,
                              hipStream_t stream) {
  (void)in_sizes; (void)n_in; (void)out_size; (void)ws_size;

  const float* x   = (const float*)d_in[0];
  const int*   mk  = (const int*)d_in[1];
  const float* Wq  = (const float*)d_in[2];
  const float* bq  = (const float*)d_in[3];
  const float* Wk  = (const float*)d_in[4];
  const float* bk  = (const float*)d_in[5];
  const float* Wv  = (const float*)d_in[6];
  const float* bv  = (const float*)d_in[7];
  const float* Wo  = (const float*)d_in[8];
  const float* bo  = (const float*)d_in[9];
  const float* W1  = (const float*)d_in[10];
  const float* b1  = (const float*)d_in[11];
  const float* W2  = (const float*)d_in[12];
  const float* b2  = (const float*)d_in[13];
  const float* g1  = (const float*)d_in[14];
  const float* be1 = (const float*)d_in[15];
  const float* g2  = (const float*)d_in[16];
  const float* be2 = (const float*)d_in[17];
  float* outp = (float*)d_out;

  // workspace arena: 8 regions x 32MB (bf16, 16777216 elems each). Peak 256MB.
  const size_t R = 16777216;
  u16* xb  = (u16*)d_ws;       // [0] x bf16 (dead after V gemm)
  u16* wb  = xb + R;           // [1] weight staging (reused per GEMM)
  u16* qb  = wb + R;           // [2] q
  u16* kb  = qb + R;           // [3] k
  u16* vt  = kb + R;           // [4] V transposed [B][H][128][1024]
  u16* ao  = vt + R;           // [5] attention out (pre-Wo)
  u64* mbt = (u64*)d_ws;       // [0] mask bitmask (after xb dead), 128 KB
  u16* ap  = qb;               // [2] attn projection (q dead)
  u16* x1  = kb;               // [3] post-LN1 (k dead)
  u16* hb  = vt;               // [4..7] FFN hidden 8192x8192 (vt, ao dead)
  u16* ffn = xb;               // [0] FFN out

  auto cvt = [&](const float* src, u16* dst, int n) {
    cvt_f32_bf16<<<dim3((n + 1023) / 1024), dim3(256), 0, stream>>>(src, dst, n);
  };

  cvt(x, xb, Mc * Dc);

  // QKV projections (V written directly in [b][h][d][s] transposed layout)
  cvt(Wq, wb, Dc * Dc);
  gemm_bt<0><<<dim3(64 * 16), dim3(256), 0, stream>>>(xb, wb, bq, qb, Mc, Dc, Dc);
  cvt(Wk, wb, Dc * Dc);
  gemm_bt<0><<<dim3(64 * 16), dim3(256), 0, stream>>>(xb, wb, bk, kb, Mc, Dc, Dc);
  cvt(Wv, wb, Dc * Dc);
  gemm_bt<2><<<dim3(64 * 16), dim3(256), 0, stream>>>(xb, wb, bv, vt, Mc, Dc, Dc);

  // mask bitmask (xb region is dead now)
  mask_bits<<<dim3(64), dim3(256), 0, stream>>>(mk, mbt);

  // attention
  attn_mfma<<<dim3(Bc * Hc * (Sc / 128)), dim3(256), 0, stream>>>(qb, kb, vt, mbt, ao);

  // output projection + LN1
  cvt(Wo, wb, Dc * Dc);
  gemm_bt<0><<<dim3(64 * 16), dim3(256), 0, stream>>>(ao, wb, bo, ap, Mc, Dc, Dc);
  ln_kernel<0, 1><<<dim3(Mc), dim3(256), 0, stream>>>(ap, x, g1, be1, x1);

  // FFN
  cvt(W1, wb, FFc * Dc);
  gemm_bt<1><<<dim3(64 * 64), dim3(256), 0, stream>>>(x1, wb, b1, hb, Mc, FFc, Dc);
  cvt(W2, wb, Dc * FFc);
  gemm_bt<0><<<dim3(64 * 16), dim3(256), 0, stream>>>(hb, wb, b2, ffn, Mc, Dc, FFc);
  ln_kernel<1, 0><<<dim3(Mc), dim3(256), 0, stream>>>(ffn, x1, g2, be2, outp);
}

// Round 5
// 1201.421 us; speedup vs baseline: 3.5959x; 1.2848x over previous
//
#include <hip/hip_runtime.h>
#include <cstdint>
#include <cstddef>

// ---------------------------------------------------------------------------
// EncoderLayer: B=8 S=1024 D=2048 H=16 Dh=128 FF=8192, fp32 in/out, bf16 compute
// ---------------------------------------------------------------------------

typedef unsigned short u16;
typedef unsigned int   u32;
typedef unsigned long long u64;
typedef __attribute__((ext_vector_type(8))) short short8;   // 8 x bf16 (4 VGPR)
typedef __attribute__((ext_vector_type(4))) float f32x4;

constexpr int Bc  = 8;
constexpr int Sc  = 1024;
constexpr int Dc  = 2048;
constexpr int Hc  = 16;
constexpr int Dhc = 128;
constexpr int FFc = 8192;
constexpr int Mc  = Bc * Sc;   // 8192 rows

// ---- bf16 helpers (manual, RNE) -------------------------------------------
__device__ __forceinline__ u16 f2b(float f) {
  u32 u = __builtin_bit_cast(u32, f);
  u += 0x7fffu + ((u >> 16) & 1u);
  return (u16)(u >> 16);
}
__device__ __forceinline__ u32 pack2(float a, float b) {
  return (u32)f2b(a) | ((u32)f2b(b) << 16);
}
__device__ __forceinline__ void unpack8(uint4 u, float* f) {
  u32 w[4] = {u.x, u.y, u.z, u.w};
#pragma unroll
  for (int i = 0; i < 4; ++i) {
    f[2 * i + 0] = __builtin_bit_cast(float, w[i] << 16);
    f[2 * i + 1] = __builtin_bit_cast(float, w[i] & 0xffff0000u);
  }
}

#define GLOAD_LDS16(gp, lp)                                                    \
  __builtin_amdgcn_global_load_lds(                                            \
      (const __attribute__((address_space(1))) void*)(gp),                     \
      (__attribute__((address_space(3))) void*)(lp), 16, 0, 0)

// ---- f32 -> bf16 conversion -----------------------------------------------
__global__ __launch_bounds__(256) void cvt_f32_bf16(const float* __restrict__ in,
                                                    u16* __restrict__ out, int n) {
  int i = (blockIdx.x * 256 + threadIdx.x) << 2;
  if (i >= n) return;
  float4 v = *(const float4*)(in + i);
  ushort4 o;
  o.x = f2b(v.x); o.y = f2b(v.y); o.z = f2b(v.z); o.w = f2b(v.w);
  *(ushort4*)(out + i) = o;
}

// ---- mask -> bitmask: mb[s][w] bit i = (mask[s][w*64+i] != 0) --------------
__global__ __launch_bounds__(256) void mask_bits(const int* __restrict__ mask,
                                                 u64* __restrict__ mb) {
  int t = blockIdx.x * 256 + threadIdx.x;   // 16384 = 1024 * 16
  int r = t >> 4, wd = t & 15;
  const int* p = mask + (size_t)r * Sc + wd * 64;
  u64 bits = 0;
#pragma unroll 16
  for (int i = 0; i < 64; i += 4) {
    int4 q = *(const int4*)(p + i);
    bits |= (u64)(q.x != 0) << (i + 0);
    bits |= (u64)(q.y != 0) << (i + 1);
    bits |= (u64)(q.z != 0) << (i + 2);
    bits |= (u64)(q.w != 0) << (i + 3);
  }
  mb[t] = bits;
}

// ---- 256x256 triple-buffered bf16 GEMM: C = A(M,K).Bt(N,K)^T + bias --------
// 8 waves (2Mx4N), BK=32. LDS: 3 x (A 256x32 + B 256x32) = 96 KB, st_16x32
// swizzle (pre-swizzled global_load_lds source + swizzled ds_read).
// Iteration t: read buf[t%3]; stage tile t+2 into buf[(t+2)%3] (A in phase 0,
// B in phase 1). Gate: vmcnt(4) while staging continues, vmcnt(0) on the tail
// iterations (this closes the round-4 race: the final tiles' loads are now
// provably landed before their reads).
// MODE 0: bf16 out. MODE 1: ReLU + bf16 out. MODE 2: vt[b][h][d][s] write.
template <int MODE>
__global__ __launch_bounds__(512, 2) void gemm256tb(const u16* __restrict__ A,
                                                    const u16* __restrict__ Bt,
                                                    const float* __restrict__ bias,
                                                    u16* __restrict__ C,
                                                    int M, int N, int K) {
  __shared__ u16 Abuf[3][256 * 32];   // 48 KB
  __shared__ u16 Bbuf[3][256 * 32];   // 48 KB

  const int nbn = N >> 8;
  const int nwg = (M >> 8) * nbn;
  int bid = blockIdx.x;
  int sw = (bid & 7) * (nwg >> 3) + (bid >> 3);   // nwg multiple of 8 always
  const int m0 = (sw / nbn) << 8;
  const int n0 = (sw % nbn) << 8;

  const int tid  = threadIdx.x;
  const int lane = tid & 63;
  const int w    = tid >> 6;        // wave 0..7
  const int wm   = w >> 2;          // 0..1  (M half)
  const int wn   = w & 3;           // 0..3  (N quarter)

  const int rowA = lane & 15;
  const int g4   = lane >> 4;

  // Stage-source pre-swizzle: lane l writes bytes [l*16, l*16+16) of its
  // wave's 1024B subtile linearly; inverse st_16x32 swizzle gives the logical
  // (row,col) whose data belongs there. XOR touches only byte-bit 5.
  const int p16  = lane << 4;
  const int wsw  = p16 ^ (((p16 >> 9) & 1) << 5);
  const int s_rr = wsw >> 6;            // row 0..15 within subtile
  const int s_cc = (wsw & 63) >> 1;     // col elem 0/8/16/24

  // ds_read swizzled byte offset within a 1024B subtile
  const int sb = (rowA * 64 + g4 * 16) ^ (((rowA >> 3) & 1) << 5);

  const int NT = K >> 5;   // K-tiles (>= 64 for all shapes here)

  const u16* Asrc = A  + (size_t)(m0 + w * 32 + s_rr) * K + s_cc;
  const u16* Bsrc = Bt + (size_t)(n0 + w * 32 + s_rr) * K + s_cc;

  // wave w stages subtiles 2w, 2w+1 (rows w*32 .. w*32+31) of a 256x32 tile
  auto stageA = [&](int buf, int tt) {
#pragma unroll
    for (int i = 0; i < 2; ++i)
      GLOAD_LDS16(Asrc + (size_t)i * 16 * K + tt * 32,
                  &Abuf[buf][(2 * w + i) * 512]);
  };
  auto stageB = [&](int buf, int tt) {
#pragma unroll
    for (int i = 0; i < 2; ++i)
      GLOAD_LDS16(Bsrc + (size_t)i * 16 * K + tt * 32,
                  &Bbuf[buf][(2 * w + i) * 512]);
  };

  f32x4 acc[8][4];
#pragma unroll
  for (int m = 0; m < 8; ++m)
#pragma unroll
    for (int n = 0; n < 4; ++n) acc[m][n] = (f32x4){0.f, 0.f, 0.f, 0.f};

  // Prologue: stage tiles 0 and 1; gate so tile 0 (first 4 loads) has landed.
  stageA(0, 0); stageB(0, 0);
  stageA(1, 1); stageB(1, 1);
  asm volatile("s_waitcnt vmcnt(4)" ::: "memory");
  __builtin_amdgcn_s_barrier();

  for (int t = 0; t < NT; ++t) {
    const int rd  = t % 3;
    const int wr_ = (t + 2) % 3;
    const bool st = (t + 2) < NT;

    // ---- phase 0: read B(all) + A(m0..3); stage A of tile t+2 --------------
    short8 bF[4], aF[4];
#pragma unroll
    for (int n = 0; n < 4; ++n)
      bF[n] = *(const short8*)((const char*)&Bbuf[rd][(wn * 4 + n) * 512] + sb);
#pragma unroll
    for (int i = 0; i < 4; ++i)
      aF[i] = *(const short8*)((const char*)&Abuf[rd][(wm * 8 + i) * 512] + sb);
    if (st) stageA(wr_, t + 2);
    __builtin_amdgcn_s_barrier();
    asm volatile("s_waitcnt lgkmcnt(0)" ::: "memory");
    __builtin_amdgcn_sched_barrier(0);
    __builtin_amdgcn_s_setprio(1);
#pragma unroll
    for (int i = 0; i < 4; ++i)
#pragma unroll
      for (int n = 0; n < 4; ++n)
        acc[i][n] = __builtin_amdgcn_mfma_f32_16x16x32_bf16(aF[i], bF[n], acc[i][n], 0, 0, 0);
    __builtin_amdgcn_s_setprio(0);
    __builtin_amdgcn_s_barrier();

    // ---- phase 1: read A(m4..7); stage B of tile t+2; gate -----------------
#pragma unroll
    for (int i = 0; i < 4; ++i)
      aF[i] = *(const short8*)((const char*)&Abuf[rd][(wm * 8 + 4 + i) * 512] + sb);
    if (st) stageB(wr_, t + 2);
    __builtin_amdgcn_s_barrier();
    asm volatile("s_waitcnt lgkmcnt(0)" ::: "memory");
    __builtin_amdgcn_sched_barrier(0);
    __builtin_amdgcn_s_setprio(1);
#pragma unroll
    for (int i = 0; i < 4; ++i)
#pragma unroll
      for (int n = 0; n < 4; ++n)
        acc[4 + i][n] = __builtin_amdgcn_mfma_f32_16x16x32_bf16(aF[i], bF[n], acc[4 + i][n], 0, 0, 0);
    __builtin_amdgcn_s_setprio(0);
    if (st) { asm volatile("s_waitcnt vmcnt(4)" ::: "memory"); }
    else    { asm volatile("s_waitcnt vmcnt(0)" ::: "memory"); }
    __builtin_amdgcn_s_barrier();
  }

  // ---- epilogue: C/D layout col=lane&15, row=(lane>>4)*4+j ------------------
  const int ci = lane & 15;
  const int ri = g4 << 2;
#pragma unroll
  for (int n = 0; n < 4; ++n) {
    int col  = n0 + wn * 64 + n * 16 + ci;
    float bv = bias[col];
#pragma unroll
    for (int m = 0; m < 8; ++m) {
      int row0 = m0 + wm * 128 + m * 16 + ri;
      if (MODE == 2) {
        ushort4 pk;
        pk.x = f2b(acc[m][n][0] + bv);
        pk.y = f2b(acc[m][n][1] + bv);
        pk.z = f2b(acc[m][n][2] + bv);
        pk.w = f2b(acc[m][n][3] + bv);
        size_t addr = ((size_t)((row0 >> 10) * Hc + (col >> 7)) * 128 + (col & 127)) * 1024
                      + (row0 & 1023);
        *(ushort4*)(C + addr) = pk;
      } else {
#pragma unroll
        for (int j = 0; j < 4; ++j) {
          float v = acc[m][n][j] + bv;
          if (MODE == 1) v = fmaxf(v, 0.f);
          C[(size_t)(row0 + j) * N + col] = f2b(v);
        }
      }
    }
  }
}

// ---- MFMA flash attention --------------------------------------------------
// Block: 256 thr (4 waves). QBLK=128 (wave owns 32 q-rows), KVBLK=64.
__global__ __launch_bounds__(256, 2) void attn_mfma(
    const u16* __restrict__ qb,   // [B*S][D]
    const u16* __restrict__ kb,   // [B*S][D]
    const u16* __restrict__ vt,   // [B*H][128][1024]   (d, s)
    const u64* __restrict__ mb,   // [S][16] bitmask
    u16* __restrict__ ob)         // [B*S][D]
{
  __shared__ u16 Ks[64 * 128];    // 16 KB, byte ^= ((krow&7)<<4), row stride 256B
  __shared__ u16 Vts[128 * 64];   // 16 KB, byte ^= ((drow&7)<<4), row stride 128B
  __shared__ u16 Ps[4][32 * 64];  // 16 KB, per-wave P, row stride 128B

  const int bid = blockIdx.x;
  const int l   = (bid & 7) * 128 + (bid >> 3);   // XCD-chunked
  const int qt  = l & 7;
  const int bh  = l >> 3;
  const int h   = bh & (Hc - 1);
  const int b   = bh >> 4;
  const int q0  = qt * 128;

  const int tid  = threadIdx.x;
  const int lane = tid & 63;
  const int w    = tid >> 6;
  const int rowA = lane & 15;
  const int g4   = lane >> 4;
  const int kq16 = g4 << 3;
  const int ri   = g4 << 2;

  const size_t tokbase = (size_t)b * Sc * Dc + (size_t)h * Dhc;
  const size_t vtbase  = (size_t)bh * 128 * 1024;
  const int qwbase = q0 + w * 32;

  short8 qf[2][4];
#pragma unroll
  for (int m = 0; m < 2; ++m)
#pragma unroll
    for (int kk = 0; kk < 4; ++kk)
      qf[m][kk] = *reinterpret_cast<const short8*>(
          qb + tokbase + (size_t)(qwbase + m * 16 + rowA) * Dc + kk * 32 + kq16);

  f32x4 O[2][8];
#pragma unroll
  for (int m = 0; m < 2; ++m)
#pragma unroll
    for (int n = 0; n < 8; ++n) O[m][n] = (f32x4){0.f, 0.f, 0.f, 0.f};
  float mrow[2][4], lrow[2][4];
#pragma unroll
  for (int m = 0; m < 2; ++m)
#pragma unroll
    for (int j = 0; j < 4; ++j) { mrow[m][j] = -INFINITY; lrow[m][j] = 0.f; }

  const float scale = 0.08838834764831845f;   // 1/sqrt(128)

  for (int kt = 0; kt < Sc / 64; ++kt) {
    const int k0 = kt * 64;
    __syncthreads();
#pragma unroll
    for (int i = 0; i < 4; ++i) {
      int chunk = w * 4 + i;
      int gb = (chunk * 64 + lane) * 16;
      int L  = gb ^ (((gb >> 8) & 7) << 4);
      int row = L >> 8, ce = (L & 255) >> 1;
      GLOAD_LDS16(kb + tokbase + (size_t)(k0 + row) * Dc + ce, &Ks[chunk * 512]);
    }
#pragma unroll
    for (int i = 0; i < 4; ++i) {
      int chunk = w * 4 + i;
      int gb = (chunk * 64 + lane) * 16;
      int L  = gb ^ (((gb >> 7) & 7) << 4);
      int row = L >> 7, ce = (L & 127) >> 1;
      GLOAD_LDS16(vt + vtbase + (size_t)row * 1024 + k0 + ce, &Vts[chunk * 512]);
    }
    __syncthreads();

    f32x4 s[2][4];
#pragma unroll
    for (int m = 0; m < 2; ++m)
#pragma unroll
      for (int n = 0; n < 4; ++n) s[m][n] = (f32x4){0.f, 0.f, 0.f, 0.f};
#pragma unroll
    for (int kk = 0; kk < 4; ++kk) {
      short8 bfk[4];
#pragma unroll
      for (int n = 0; n < 4; ++n) {
        int krow = n * 16 + rowA;
        int by = (krow * 256 + kk * 64 + (g4 << 4)) ^ ((krow & 7) << 4);
        bfk[n] = *reinterpret_cast<const short8*>((const char*)Ks + by);
      }
#pragma unroll
      for (int m = 0; m < 2; ++m)
#pragma unroll
        for (int n = 0; n < 4; ++n)
          s[m][n] = __builtin_amdgcn_mfma_f32_16x16x32_bf16(qf[m][kk], bfk[n], s[m][n], 0, 0, 0);
    }

    float alpha[2][4];
#pragma unroll
    for (int m = 0; m < 2; ++m) {
      u64 wb_[4];
#pragma unroll
      for (int j = 0; j < 4; ++j)
        wb_[j] = mb[(size_t)(qwbase + m * 16 + ri + j) * 16 + kt];
#pragma unroll
      for (int j = 0; j < 4; ++j) {
        float pv[4];
        float mx = -3.0e38f;
#pragma unroll
        for (int n = 0; n < 4; ++n) {
          float x = s[m][n][j] * scale;
          if (!((wb_[j] >> (n * 16 + rowA)) & 1)) x = -1e9f;
          pv[n] = x;
          mx = fmaxf(mx, x);
        }
        mx = fmaxf(mx, __shfl_xor(mx, 1));
        mx = fmaxf(mx, __shfl_xor(mx, 2));
        mx = fmaxf(mx, __shfl_xor(mx, 4));
        mx = fmaxf(mx, __shfl_xor(mx, 8));
        float mnew = fmaxf(mrow[m][j], mx);
        float a = __expf(mrow[m][j] - mnew);
        mrow[m][j] = mnew;
        alpha[m][j] = a;
        float rs = 0.f;
#pragma unroll
        for (int n = 0; n < 4; ++n) {
          float p = __expf(pv[n] - mnew);
          pv[n] = p;
          rs += p;
        }
        rs += __shfl_xor(rs, 1);
        rs += __shfl_xor(rs, 2);
        rs += __shfl_xor(rs, 4);
        rs += __shfl_xor(rs, 8);
        lrow[m][j] = lrow[m][j] * a + rs;
        int prow = m * 16 + ri + j;
#pragma unroll
        for (int n = 0; n < 4; ++n) {
          int by = (prow * 128 + 2 * (n * 16 + rowA)) ^ ((prow & 7) << 4);
          *(u16*)((char*)Ps[w] + by) = f2b(pv[n]);
        }
      }
    }
    asm volatile("s_waitcnt lgkmcnt(0)" ::: "memory");

#pragma unroll
    for (int m = 0; m < 2; ++m)
#pragma unroll
      for (int n = 0; n < 8; ++n)
#pragma unroll
        for (int j = 0; j < 4; ++j) O[m][n][j] *= alpha[m][j];

    short8 pa[2][2];
#pragma unroll
    for (int m = 0; m < 2; ++m)
#pragma unroll
      for (int kk = 0; kk < 2; ++kk) {
        int prow = m * 16 + rowA;
        int by = (prow * 128 + kk * 64 + (g4 << 4)) ^ ((prow & 7) << 4);
        pa[m][kk] = *reinterpret_cast<const short8*>((const char*)Ps[w] + by);
      }
#pragma unroll
    for (int kk = 0; kk < 2; ++kk)
#pragma unroll
      for (int n = 0; n < 8; ++n) {
        int drow = n * 16 + rowA;
        int by = (drow * 128 + kk * 64 + (g4 << 4)) ^ ((drow & 7) << 4);
        short8 bfv = *reinterpret_cast<const short8*>((const char*)Vts + by);
#pragma unroll
        for (int m = 0; m < 2; ++m)
          O[m][n] = __builtin_amdgcn_mfma_f32_16x16x32_bf16(pa[m][kk], bfv, O[m][n], 0, 0, 0);
      }
  }

  float inv[2][4];
#pragma unroll
  for (int m = 0; m < 2; ++m)
#pragma unroll
    for (int j = 0; j < 4; ++j) inv[m][j] = 1.f / lrow[m][j];
#pragma unroll
  for (int m = 0; m < 2; ++m)
#pragma unroll
    for (int n = 0; n < 8; ++n) {
      int dcol = n * 16 + rowA;
#pragma unroll
      for (int j = 0; j < 4; ++j) {
        int qg = qwbase + m * 16 + ri + j;
        ob[tokbase + (size_t)qg * Dc + dcol] = f2b(O[m][n][j] * inv[m][j]);
      }
    }
}

// ---- fused residual + LayerNorm -------------------------------------------
template <int RES_BF16, int OUT_BF16>
__global__ __launch_bounds__(256) void ln_kernel(const u16* __restrict__ a,
                                                 const void* __restrict__ resid,
                                                 const float* __restrict__ g,
                                                 const float* __restrict__ be,
                                                 void* __restrict__ out) {
  int row = blockIdx.x;
  int tid = threadIdx.x;
  int c0  = tid << 3;

  float v[8], vr[8];
  uint4 ua = *(const uint4*)(a + (size_t)row * Dc + c0);
  unpack8(ua, v);
  if (RES_BF16) {
    uint4 ur = *(const uint4*)((const u16*)resid + (size_t)row * Dc + c0);
    unpack8(ur, vr);
  } else {
    const float* rp = (const float*)resid + (size_t)row * Dc + c0;
    float4 f0 = *(const float4*)rp;
    float4 f1 = *(const float4*)(rp + 4);
    vr[0] = f0.x; vr[1] = f0.y; vr[2] = f0.z; vr[3] = f0.w;
    vr[4] = f1.x; vr[5] = f1.y; vr[6] = f1.z; vr[7] = f1.w;
  }

  float s = 0.f, ss = 0.f;
#pragma unroll
  for (int j = 0; j < 8; ++j) {
    v[j] += vr[j];
    s += v[j];
    ss += v[j] * v[j];
  }
#pragma unroll
  for (int off = 32; off; off >>= 1) {
    s  += __shfl_down(s, off);
    ss += __shfl_down(ss, off);
  }
  __shared__ float rs[4], rss[4], stat[2];
  if ((tid & 63) == 0) { rs[tid >> 6] = s; rss[tid >> 6] = ss; }
  __syncthreads();
  if (tid == 0) {
    float t  = rs[0] + rs[1] + rs[2] + rs[3];
    float tt = rss[0] + rss[1] + rss[2] + rss[3];
    float mean = t * (1.f / Dc);
    float var  = tt * (1.f / Dc) - mean * mean;
    stat[0] = mean;
    stat[1] = rsqrtf(var + 1e-5f);
  }
  __syncthreads();
  float mean = stat[0], rstd = stat[1];

  float y[8];
#pragma unroll
  for (int j = 0; j < 8; ++j) y[j] = (v[j] - mean) * rstd * g[c0 + j] + be[c0 + j];

  if (OUT_BF16) {
    uint4 o;
    o.x = pack2(y[0], y[1]); o.y = pack2(y[2], y[3]);
    o.z = pack2(y[4], y[5]); o.w = pack2(y[6], y[7]);
    *(uint4*)((u16*)out + (size_t)row * Dc + c0) = o;
  } else {
    float* op = (float*)out + (size_t)row * Dc + c0;
    *(float4*)op       = (float4){y[0], y[1], y[2], y[3]};
    *(float4*)(op + 4) = (float4){y[4], y[5], y[6], y[7]};
  }
}

// ---------------------------------------------------------------------------
extern "C" void kernel_launch(void* const* d_in, const int* in_sizes, int n_in,
                              void* d_out, int out_size, void* d_ws, size_t ws_size,
                              hipStream_t stream) {
  (void)in_sizes; (void)n_in; (void)out_size; (void)ws_size;

  const float* x   = (const float*)d_in[0];
  const int*   mk  = (const int*)d_in[1];
  const float* Wq  = (const float*)d_in[2];
  const float* bq  = (const float*)d_in[3];
  const float* Wk  = (const float*)d_in[4];
  const float* bk  = (const float*)d_in[5];
  const float* Wv  = (const float*)d_in[6];
  const float* bv  = (const float*)d_in[7];
  const float* Wo  = (const float*)d_in[8];
  const float* bo  = (const float*)d_in[9];
  const float* W1  = (const float*)d_in[10];
  const float* b1  = (const float*)d_in[11];
  const float* W2  = (const float*)d_in[12];
  const float* b2  = (const float*)d_in[13];
  const float* g1  = (const float*)d_in[14];
  const float* be1 = (const float*)d_in[15];
  const float* g2  = (const float*)d_in[16];
  const float* be2 = (const float*)d_in[17];
  float* outp = (float*)d_out;

  // workspace arena: 8 regions x 32MB (bf16, 16777216 elems each). Peak 256MB.
  const size_t R = 16777216;
  u16* xb  = (u16*)d_ws;       // [0] x bf16 (dead after V gemm)
  u16* wb  = xb + R;           // [1] weight staging (reused per GEMM)
  u16* qb  = wb + R;           // [2] q
  u16* kb  = qb + R;           // [3] k
  u16* vt  = kb + R;           // [4] V transposed [B][H][128][1024]
  u16* ao  = vt + R;           // [5] attention out (pre-Wo)
  u64* mbt = (u64*)d_ws;       // [0] mask bitmask (after xb dead), 128 KB
  u16* ap  = qb;               // [2] attn projection (q dead)
  u16* x1  = kb;               // [3] post-LN1 (k dead)
  u16* hb  = vt;               // [4..7] FFN hidden 8192x8192 (vt, ao dead)
  u16* ffn = xb;               // [0] FFN out

  auto cvt = [&](const float* src, u16* dst, int n) {
    cvt_f32_bf16<<<dim3((n + 1023) / 1024), dim3(256), 0, stream>>>(src, dst, n);
  };

  cvt(x, xb, Mc * Dc);

  // QKV projections (V written directly in [b][h][d][s] transposed layout)
  cvt(Wq, wb, Dc * Dc);
  gemm256tb<0><<<dim3(32 * 8), dim3(512), 0, stream>>>(xb, wb, bq, qb, Mc, Dc, Dc);
  cvt(Wk, wb, Dc * Dc);
  gemm256tb<0><<<dim3(32 * 8), dim3(512), 0, stream>>>(xb, wb, bk, kb, Mc, Dc, Dc);
  cvt(Wv, wb, Dc * Dc);
  gemm256tb<2><<<dim3(32 * 8), dim3(512), 0, stream>>>(xb, wb, bv, vt, Mc, Dc, Dc);

  // mask bitmask (xb region is dead now)
  mask_bits<<<dim3(64), dim3(256), 0, stream>>>(mk, mbt);

  // attention
  attn_mfma<<<dim3(Bc * Hc * (Sc / 128)), dim3(256), 0, stream>>>(qb, kb, vt, mbt, ao);

  // output projection + LN1
  cvt(Wo, wb, Dc * Dc);
  gemm256tb<0><<<dim3(32 * 8), dim3(512), 0, stream>>>(ao, wb, bo, ap, Mc, Dc, Dc);
  ln_kernel<0, 1><<<dim3(Mc), dim3(256), 0, stream>>>(ap, x, g1, be1, x1);

  // FFN
  cvt(W1, wb, FFc * Dc);
  gemm256tb<1><<<dim3(32 * 32), dim3(512), 0, stream>>>(x1, wb, b1, hb, Mc, FFc, Dc);
  cvt(W2, wb, Dc * FFc);
  gemm256tb<0><<<dim3(32 * 8), dim3(512), 0, stream>>>(hb, wb, b2, ffn, Mc, Dc, FFc);
  ln_kernel<1, 0><<<dim3(Mc), dim3(256), 0, stream>>>(ffn, x1, g2, be2, outp);
}

// Round 6
// 1154.547 us; speedup vs baseline: 3.7419x; 1.0406x over previous
//
#include <hip/hip_runtime.h>
#include <cstdint>
#include <cstddef>

// ---------------------------------------------------------------------------
// EncoderLayer: B=8 S=1024 D=2048 H=16 Dh=128 FF=8192, fp32 in/out, bf16 compute
// ---------------------------------------------------------------------------

typedef unsigned short u16;
typedef unsigned int   u32;
typedef unsigned long long u64;
typedef __attribute__((ext_vector_type(8))) short short8;   // 8 x bf16 (4 VGPR)
typedef __attribute__((ext_vector_type(4))) float f32x4;

constexpr int Bc  = 8;
constexpr int Sc  = 1024;
constexpr int Dc  = 2048;
constexpr int Hc  = 16;
constexpr int Dhc = 128;
constexpr int FFc = 8192;
constexpr int Mc  = Bc * Sc;   // 8192 rows

// ---- bf16 helpers (manual, RNE) -------------------------------------------
__device__ __forceinline__ u16 f2b(float f) {
  u32 u = __builtin_bit_cast(u32, f);
  u += 0x7fffu + ((u >> 16) & 1u);
  return (u16)(u >> 16);
}
__device__ __forceinline__ u32 pack2(float a, float b) {
  return (u32)f2b(a) | ((u32)f2b(b) << 16);
}
__device__ __forceinline__ void unpack8(uint4 u, float* f) {
  u32 w[4] = {u.x, u.y, u.z, u.w};
#pragma unroll
  for (int i = 0; i < 4; ++i) {
    f[2 * i + 0] = __builtin_bit_cast(float, w[i] << 16);
    f[2 * i + 1] = __builtin_bit_cast(float, w[i] & 0xffff0000u);
  }
}

#define GLOAD_LDS16(gp, lp)                                                    \
  __builtin_amdgcn_global_load_lds(                                            \
      (const __attribute__((address_space(1))) void*)(gp),                     \
      (__attribute__((address_space(3))) void*)(lp), 16, 0, 0)

// ---- f32 -> bf16 conversion -----------------------------------------------
__global__ __launch_bounds__(256) void cvt_f32_bf16(const float* __restrict__ in,
                                                    u16* __restrict__ out, int n) {
  int i = (blockIdx.x * 256 + threadIdx.x) << 2;
  if (i >= n) return;
  float4 v = *(const float4*)(in + i);
  ushort4 o;
  o.x = f2b(v.x); o.y = f2b(v.y); o.z = f2b(v.z); o.w = f2b(v.w);
  *(ushort4*)(out + i) = o;
}

// ---- mask -> bitmask: mb[s][w] bit i = (mask[s][w*64+i] != 0) --------------
__global__ __launch_bounds__(256) void mask_bits(const int* __restrict__ mask,
                                                 u64* __restrict__ mb) {
  int t = blockIdx.x * 256 + threadIdx.x;   // 16384 = 1024 * 16
  int r = t >> 4, wd = t & 15;
  const int* p = mask + (size_t)r * Sc + wd * 64;
  u64 bits = 0;
#pragma unroll 16
  for (int i = 0; i < 64; i += 4) {
    int4 q = *(const int4*)(p + i);
    bits |= (u64)(q.x != 0) << (i + 0);
    bits |= (u64)(q.y != 0) << (i + 1);
    bits |= (u64)(q.z != 0) << (i + 2);
    bits |= (u64)(q.w != 0) << (i + 3);
  }
  mb[t] = bits;
}

// ---- 256x256 4-deep-pipelined bf16 GEMM: C = A(M,K).Bt(N,K)^T + bias -------
// 8 waves (2Mx4N), BK=32. LDS: 4 x (A 256x32 + B 256x32) = 128 KB, st_16x32
// swizzle (pre-swizzled global_load_lds source + swizzled ds_read).
// Iteration t: read buf[t&3]; stage tile t+3 into buf[(t+3)&3] (A in phase 0,
// B in phase 1). Gate at end of iter t: tile t+1 must have landed ->
// vmcnt(8) while 2 tiles remain in flight, peel to vmcnt(4)/vmcnt(0) at tail.
// (Deeper than round-5's triple buffer: load->use lead ~2.3 iterations, which
// covers L2/HBM latency; round-5's 1-iteration lead stalled every gate.)
// MODE 0: bf16 out. MODE 1: ReLU + bf16 out. MODE 2: vt[b][h][d][s] write.
template <int MODE>
__global__ __launch_bounds__(512, 2) void gemm256tb(const u16* __restrict__ A,
                                                    const u16* __restrict__ Bt,
                                                    const float* __restrict__ bias,
                                                    u16* __restrict__ C,
                                                    int M, int N, int K) {
  __shared__ u16 Abuf[4][256 * 32];   // 64 KB
  __shared__ u16 Bbuf[4][256 * 32];   // 64 KB

  const int nbn = N >> 8;
  const int nwg = (M >> 8) * nbn;
  int bid = blockIdx.x;
  int sw = (bid & 7) * (nwg >> 3) + (bid >> 3);   // nwg multiple of 8 always
  const int m0 = (sw / nbn) << 8;
  const int n0 = (sw % nbn) << 8;

  const int tid  = threadIdx.x;
  const int lane = tid & 63;
  const int w    = tid >> 6;        // wave 0..7
  const int wm   = w >> 2;          // 0..1  (M half)
  const int wn   = w & 3;           // 0..3  (N quarter)

  const int rowA = lane & 15;
  const int g4   = lane >> 4;

  // Stage-source pre-swizzle: lane l writes bytes [l*16, l*16+16) of its
  // wave's 1024B subtile linearly; inverse st_16x32 swizzle gives the logical
  // (row,col) whose data belongs there. XOR touches only byte-bit 5.
  const int p16  = lane << 4;
  const int wsw  = p16 ^ (((p16 >> 9) & 1) << 5);
  const int s_rr = wsw >> 6;            // row 0..15 within subtile
  const int s_cc = (wsw & 63) >> 1;     // col elem 0/8/16/24

  // ds_read swizzled byte offset within a 1024B subtile
  const int sb = (rowA * 64 + g4 * 16) ^ (((rowA >> 3) & 1) << 5);

  const int NT = K >> 5;   // K-tiles (>= 64 for all shapes here)

  const u16* Asrc = A  + (size_t)(m0 + w * 32 + s_rr) * K + s_cc;
  const u16* Bsrc = Bt + (size_t)(n0 + w * 32 + s_rr) * K + s_cc;

  // wave w stages subtiles 2w, 2w+1 (rows w*32 .. w*32+31) of a 256x32 tile
  auto stageA = [&](int buf, int tt) {
#pragma unroll
    for (int i = 0; i < 2; ++i)
      GLOAD_LDS16(Asrc + (size_t)i * 16 * K + tt * 32,
                  &Abuf[buf][(2 * w + i) * 512]);
  };
  auto stageB = [&](int buf, int tt) {
#pragma unroll
    for (int i = 0; i < 2; ++i)
      GLOAD_LDS16(Bsrc + (size_t)i * 16 * K + tt * 32,
                  &Bbuf[buf][(2 * w + i) * 512]);
  };

  f32x4 acc[8][4];
#pragma unroll
  for (int m = 0; m < 8; ++m)
#pragma unroll
    for (int n = 0; n < 4; ++n) acc[m][n] = (f32x4){0.f, 0.f, 0.f, 0.f};

  // Prologue: stage tiles 0,1,2 (12 loads); gate so tile 0 has landed.
  stageA(0, 0); stageB(0, 0);
  stageA(1, 1); stageB(1, 1);
  stageA(2, 2); stageB(2, 2);
  asm volatile("s_waitcnt vmcnt(8)" ::: "memory");
  __builtin_amdgcn_s_barrier();

  for (int t = 0; t < NT; ++t) {
    const int rd  = t & 3;
    const int wr_ = (t + 3) & 3;
    const bool st = (t + 3) < NT;

    // ---- phase 0: read B(all) + A(m0..3); stage A of tile t+3 --------------
    short8 bF[4], aF[4];
#pragma unroll
    for (int n = 0; n < 4; ++n)
      bF[n] = *(const short8*)((const char*)&Bbuf[rd][(wn * 4 + n) * 512] + sb);
#pragma unroll
    for (int i = 0; i < 4; ++i)
      aF[i] = *(const short8*)((const char*)&Abuf[rd][(wm * 8 + i) * 512] + sb);
    if (st) stageA(wr_, t + 3);
    __builtin_amdgcn_s_barrier();
    asm volatile("s_waitcnt lgkmcnt(0)" ::: "memory");
    __builtin_amdgcn_sched_barrier(0);
    __builtin_amdgcn_s_setprio(1);
#pragma unroll
    for (int i = 0; i < 4; ++i)
#pragma unroll
      for (int n = 0; n < 4; ++n)
        acc[i][n] = __builtin_amdgcn_mfma_f32_16x16x32_bf16(aF[i], bF[n], acc[i][n], 0, 0, 0);
    __builtin_amdgcn_s_setprio(0);
    __builtin_amdgcn_s_barrier();

    // ---- phase 1: read A(m4..7); stage B of tile t+3; gate -----------------
#pragma unroll
    for (int i = 0; i < 4; ++i)
      aF[i] = *(const short8*)((const char*)&Abuf[rd][(wm * 8 + 4 + i) * 512] + sb);
    if (st) stageB(wr_, t + 3);
    __builtin_amdgcn_s_barrier();
    asm volatile("s_waitcnt lgkmcnt(0)" ::: "memory");
    __builtin_amdgcn_sched_barrier(0);
    __builtin_amdgcn_s_setprio(1);
#pragma unroll
    for (int i = 0; i < 4; ++i)
#pragma unroll
      for (int n = 0; n < 4; ++n)
        acc[4 + i][n] = __builtin_amdgcn_mfma_f32_16x16x32_bf16(aF[i], bF[n], acc[4 + i][n], 0, 0, 0);
    __builtin_amdgcn_s_setprio(0);
    // gate: tile t+1 landed. In-order issue; tiles t+2,t+3 may stay in flight.
    if (st)                { asm volatile("s_waitcnt vmcnt(8)" ::: "memory"); }
    else if (t + 2 < NT)   { asm volatile("s_waitcnt vmcnt(4)" ::: "memory"); }
    else                   { asm volatile("s_waitcnt vmcnt(0)" ::: "memory"); }
    __builtin_amdgcn_s_barrier();
  }

  // ---- epilogue: C/D layout col=lane&15, row=(lane>>4)*4+j ------------------
  // Loop order m->j->n so the 4 n-segments (4 x 32B) of each row are issued
  // back-to-back -> L2 write-combining into full lines (round-5 showed 2x
  // write amplification with n-outer order).
  const int ci = lane & 15;
  const int ri = g4 << 2;
  float bvv[4];
#pragma unroll
  for (int n = 0; n < 4; ++n) bvv[n] = bias[n0 + wn * 64 + n * 16 + ci];

  if (MODE == 2) {
#pragma unroll
    for (int n = 0; n < 4; ++n) {
      int col = n0 + wn * 64 + n * 16 + ci;
#pragma unroll
      for (int m = 0; m < 8; ++m) {
        int row0 = m0 + wm * 128 + m * 16 + ri;
        ushort4 pk;
        pk.x = f2b(acc[m][n][0] + bvv[n]);
        pk.y = f2b(acc[m][n][1] + bvv[n]);
        pk.z = f2b(acc[m][n][2] + bvv[n]);
        pk.w = f2b(acc[m][n][3] + bvv[n]);
        size_t addr = ((size_t)((row0 >> 10) * Hc + (col >> 7)) * 128 + (col & 127)) * 1024
                      + (row0 & 1023);
        *(ushort4*)(C + addr) = pk;
      }
    }
  } else {
#pragma unroll
    for (int m = 0; m < 8; ++m) {
      int row0 = m0 + wm * 128 + m * 16 + ri;
#pragma unroll
      for (int j = 0; j < 4; ++j) {
        u16* cp = C + (size_t)(row0 + j) * N + n0 + wn * 64 + ci;
#pragma unroll
        for (int n = 0; n < 4; ++n) {
          float v = acc[m][n][j] + bvv[n];
          if (MODE == 1) v = fmaxf(v, 0.f);
          cp[n * 16] = f2b(v);
        }
      }
    }
  }
}

// ---- MFMA flash attention --------------------------------------------------
// Block: 256 thr (4 waves). QBLK=128 (wave owns 32 q-rows), KVBLK=64.
__global__ __launch_bounds__(256, 2) void attn_mfma(
    const u16* __restrict__ qb,   // [B*S][D]
    const u16* __restrict__ kb,   // [B*S][D]
    const u16* __restrict__ vt,   // [B*H][128][1024]   (d, s)
    const u64* __restrict__ mb,   // [S][16] bitmask
    u16* __restrict__ ob)         // [B*S][D]
{
  __shared__ u16 Ks[64 * 128];    // 16 KB, byte ^= ((krow&7)<<4), row stride 256B
  __shared__ u16 Vts[128 * 64];   // 16 KB, byte ^= ((drow&7)<<4), row stride 128B
  __shared__ u16 Ps[4][32 * 64];  // 16 KB, per-wave P, row stride 128B

  const int bid = blockIdx.x;
  const int l   = (bid & 7) * 128 + (bid >> 3);   // XCD-chunked
  const int qt  = l & 7;
  const int bh  = l >> 3;
  const int h   = bh & (Hc - 1);
  const int b   = bh >> 4;
  const int q0  = qt * 128;

  const int tid  = threadIdx.x;
  const int lane = tid & 63;
  const int w    = tid >> 6;
  const int rowA = lane & 15;
  const int g4   = lane >> 4;
  const int kq16 = g4 << 3;
  const int ri   = g4 << 2;

  const size_t tokbase = (size_t)b * Sc * Dc + (size_t)h * Dhc;
  const size_t vtbase  = (size_t)bh * 128 * 1024;
  const int qwbase = q0 + w * 32;

  short8 qf[2][4];
#pragma unroll
  for (int m = 0; m < 2; ++m)
#pragma unroll
    for (int kk = 0; kk < 4; ++kk)
      qf[m][kk] = *reinterpret_cast<const short8*>(
          qb + tokbase + (size_t)(qwbase + m * 16 + rowA) * Dc + kk * 32 + kq16);

  f32x4 O[2][8];
#pragma unroll
  for (int m = 0; m < 2; ++m)
#pragma unroll
    for (int n = 0; n < 8; ++n) O[m][n] = (f32x4){0.f, 0.f, 0.f, 0.f};
  float mrow[2][4], lrow[2][4];
#pragma unroll
  for (int m = 0; m < 2; ++m)
#pragma unroll
    for (int j = 0; j < 4; ++j) { mrow[m][j] = -INFINITY; lrow[m][j] = 0.f; }

  const float scale = 0.08838834764831845f;   // 1/sqrt(128)

  for (int kt = 0; kt < Sc / 64; ++kt) {
    const int k0 = kt * 64;
    __syncthreads();
#pragma unroll
    for (int i = 0; i < 4; ++i) {
      int chunk = w * 4 + i;
      int gb = (chunk * 64 + lane) * 16;
      int L  = gb ^ (((gb >> 8) & 7) << 4);
      int row = L >> 8, ce = (L & 255) >> 1;
      GLOAD_LDS16(kb + tokbase + (size_t)(k0 + row) * Dc + ce, &Ks[chunk * 512]);
    }
#pragma unroll
    for (int i = 0; i < 4; ++i) {
      int chunk = w * 4 + i;
      int gb = (chunk * 64 + lane) * 16;
      int L  = gb ^ (((gb >> 7) & 7) << 4);
      int row = L >> 7, ce = (L & 127) >> 1;
      GLOAD_LDS16(vt + vtbase + (size_t)row * 1024 + k0 + ce, &Vts[chunk * 512]);
    }
    __syncthreads();

    f32x4 s[2][4];
#pragma unroll
    for (int m = 0; m < 2; ++m)
#pragma unroll
      for (int n = 0; n < 4; ++n) s[m][n] = (f32x4){0.f, 0.f, 0.f, 0.f};
#pragma unroll
    for (int kk = 0; kk < 4; ++kk) {
      short8 bfk[4];
#pragma unroll
      for (int n = 0; n < 4; ++n) {
        int krow = n * 16 + rowA;
        int by = (krow * 256 + kk * 64 + (g4 << 4)) ^ ((krow & 7) << 4);
        bfk[n] = *reinterpret_cast<const short8*>((const char*)Ks + by);
      }
#pragma unroll
      for (int m = 0; m < 2; ++m)
#pragma unroll
        for (int n = 0; n < 4; ++n)
          s[m][n] = __builtin_amdgcn_mfma_f32_16x16x32_bf16(qf[m][kk], bfk[n], s[m][n], 0, 0, 0);
    }

    float alpha[2][4];
#pragma unroll
    for (int m = 0; m < 2; ++m) {
      u64 wb_[4];
#pragma unroll
      for (int j = 0; j < 4; ++j)
        wb_[j] = mb[(size_t)(qwbase + m * 16 + ri + j) * 16 + kt];
#pragma unroll
      for (int j = 0; j < 4; ++j) {
        float pv[4];
        float mx = -3.0e38f;
#pragma unroll
        for (int n = 0; n < 4; ++n) {
          float x = s[m][n][j] * scale;
          if (!((wb_[j] >> (n * 16 + rowA)) & 1)) x = -1e9f;
          pv[n] = x;
          mx = fmaxf(mx, x);
        }
        mx = fmaxf(mx, __shfl_xor(mx, 1));
        mx = fmaxf(mx, __shfl_xor(mx, 2));
        mx = fmaxf(mx, __shfl_xor(mx, 4));
        mx = fmaxf(mx, __shfl_xor(mx, 8));
        float mnew = fmaxf(mrow[m][j], mx);
        float a = __expf(mrow[m][j] - mnew);
        mrow[m][j] = mnew;
        alpha[m][j] = a;
        float rs = 0.f;
#pragma unroll
        for (int n = 0; n < 4; ++n) {
          float p = __expf(pv[n] - mnew);
          pv[n] = p;
          rs += p;
        }
        rs += __shfl_xor(rs, 1);
        rs += __shfl_xor(rs, 2);
        rs += __shfl_xor(rs, 4);
        rs += __shfl_xor(rs, 8);
        lrow[m][j] = lrow[m][j] * a + rs;
        int prow = m * 16 + ri + j;
#pragma unroll
        for (int n = 0; n < 4; ++n) {
          int by = (prow * 128 + 2 * (n * 16 + rowA)) ^ ((prow & 7) << 4);
          *(u16*)((char*)Ps[w] + by) = f2b(pv[n]);
        }
      }
    }
    asm volatile("s_waitcnt lgkmcnt(0)" ::: "memory");

#pragma unroll
    for (int m = 0; m < 2; ++m)
#pragma unroll
      for (int n = 0; n < 8; ++n)
#pragma unroll
        for (int j = 0; j < 4; ++j) O[m][n][j] *= alpha[m][j];

    short8 pa[2][2];
#pragma unroll
    for (int m = 0; m < 2; ++m)
#pragma unroll
      for (int kk = 0; kk < 2; ++kk) {
        int prow = m * 16 + rowA;
        int by = (prow * 128 + kk * 64 + (g4 << 4)) ^ ((prow & 7) << 4);
        pa[m][kk] = *reinterpret_cast<const short8*>((const char*)Ps[w] + by);
      }
#pragma unroll
    for (int kk = 0; kk < 2; ++kk)
#pragma unroll
      for (int n = 0; n < 8; ++n) {
        int drow = n * 16 + rowA;
        int by = (drow * 128 + kk * 64 + (g4 << 4)) ^ ((drow & 7) << 4);
        short8 bfv = *reinterpret_cast<const short8*>((const char*)Vts + by);
#pragma unroll
        for (int m = 0; m < 2; ++m)
          O[m][n] = __builtin_amdgcn_mfma_f32_16x16x32_bf16(pa[m][kk], bfv, O[m][n], 0, 0, 0);
      }
  }

  float inv[2][4];
#pragma unroll
  for (int m = 0; m < 2; ++m)
#pragma unroll
    for (int j = 0; j < 4; ++j) inv[m][j] = 1.f / lrow[m][j];
#pragma unroll
  for (int m = 0; m < 2; ++m)
#pragma unroll
    for (int n = 0; n < 8; ++n) {
      int dcol = n * 16 + rowA;
#pragma unroll
      for (int j = 0; j < 4; ++j) {
        int qg = qwbase + m * 16 + ri + j;
        ob[tokbase + (size_t)qg * Dc + dcol] = f2b(O[m][n][j] * inv[m][j]);
      }
    }
}

// ---- fused residual + LayerNorm -------------------------------------------
template <int RES_BF16, int OUT_BF16>
__global__ __launch_bounds__(256) void ln_kernel(const u16* __restrict__ a,
                                                 const void* __restrict__ resid,
                                                 const float* __restrict__ g,
                                                 const float* __restrict__ be,
                                                 void* __restrict__ out) {
  int row = blockIdx.x;
  int tid = threadIdx.x;
  int c0  = tid << 3;

  float v[8], vr[8];
  uint4 ua = *(const uint4*)(a + (size_t)row * Dc + c0);
  unpack8(ua, v);
  if (RES_BF16) {
    uint4 ur = *(const uint4*)((const u16*)resid + (size_t)row * Dc + c0);
    unpack8(ur, vr);
  } else {
    const float* rp = (const float*)resid + (size_t)row * Dc + c0;
    float4 f0 = *(const float4*)rp;
    float4 f1 = *(const float4*)(rp + 4);
    vr[0] = f0.x; vr[1] = f0.y; vr[2] = f0.z; vr[3] = f0.w;
    vr[4] = f1.x; vr[5] = f1.y; vr[6] = f1.z; vr[7] = f1.w;
  }

  float s = 0.f, ss = 0.f;
#pragma unroll
  for (int j = 0; j < 8; ++j) {
    v[j] += vr[j];
    s += v[j];
    ss += v[j] * v[j];
  }
#pragma unroll
  for (int off = 32; off; off >>= 1) {
    s  += __shfl_down(s, off);
    ss += __shfl_down(ss, off);
  }
  __shared__ float rs[4], rss[4], stat[2];
  if ((tid & 63) == 0) { rs[tid >> 6] = s; rss[tid >> 6] = ss; }
  __syncthreads();
  if (tid == 0) {
    float t  = rs[0] + rs[1] + rs[2] + rs[3];
    float tt = rss[0] + rss[1] + rss[2] + rss[3];
    float mean = t * (1.f / Dc);
    float var  = tt * (1.f / Dc) - mean * mean;
    stat[0] = mean;
    stat[1] = rsqrtf(var + 1e-5f);
  }
  __syncthreads();
  float mean = stat[0], rstd = stat[1];

  float y[8];
#pragma unroll
  for (int j = 0; j < 8; ++j) y[j] = (v[j] - mean) * rstd * g[c0 + j] + be[c0 + j];

  if (OUT_BF16) {
    uint4 o;
    o.x = pack2(y[0], y[1]); o.y = pack2(y[2], y[3]);
    o.z = pack2(y[4], y[5]); o.w = pack2(y[6], y[7]);
    *(uint4*)((u16*)out + (size_t)row * Dc + c0) = o;
  } else {
    float* op = (float*)out + (size_t)row * Dc + c0;
    *(float4*)op       = (float4){y[0], y[1], y[2], y[3]};
    *(float4*)(op + 4) = (float4){y[4], y[5], y[6], y[7]};
  }
}

// ---------------------------------------------------------------------------
extern "C" void kernel_launch(void* const* d_in, const int* in_sizes, int n_in,
                              void* d_out, int out_size, void* d_ws, size_t ws_size,
                              hipStream_t stream) {
  (void)in_sizes; (void)n_in; (void)out_size; (void)ws_size;

  const float* x   = (const float*)d_in[0];
  const int*   mk  = (const int*)d_in[1];
  const float* Wq  = (const float*)d_in[2];
  const float* bq  = (const float*)d_in[3];
  const float* Wk  = (const float*)d_in[4];
  const float* bk  = (const float*)d_in[5];
  const float* Wv  = (const float*)d_in[6];
  const float* bv  = (const float*)d_in[7];
  const float* Wo  = (const float*)d_in[8];
  const float* bo  = (const float*)d_in[9];
  const float* W1  = (const float*)d_in[10];
  const float* b1  = (const float*)d_in[11];
  const float* W2  = (const float*)d_in[12];
  const float* b2  = (const float*)d_in[13];
  const float* g1  = (const float*)d_in[14];
  const float* be1 = (const float*)d_in[15];
  const float* g2  = (const float*)d_in[16];
  const float* be2 = (const float*)d_in[17];
  float* outp = (float*)d_out;

  // workspace arena: 8 regions x 32MB (bf16, 16777216 elems each). Peak 256MB.
  const size_t R = 16777216;
  u16* xb  = (u16*)d_ws;       // [0] x bf16 (dead after V gemm)
  u16* wb  = xb + R;           // [1] weight staging (reused per GEMM)
  u16* qb  = wb + R;           // [2] q
  u16* kb  = qb + R;           // [3] k
  u16* vt  = kb + R;           // [4] V transposed [B][H][128][1024]
  u16* ao  = vt + R;           // [5] attention out (pre-Wo)
  u64* mbt = (u64*)d_ws;       // [0] mask bitmask (after xb dead), 128 KB
  u16* ap  = qb;               // [2] attn projection (q dead)
  u16* x1  = kb;               // [3] post-LN1 (k dead)
  u16* hb  = vt;               // [4..7] FFN hidden 8192x8192 (vt, ao dead)
  u16* ffn = xb;               // [0] FFN out

  auto cvt = [&](const float* src, u16* dst, int n) {
    cvt_f32_bf16<<<dim3((n + 1023) / 1024), dim3(256), 0, stream>>>(src, dst, n);
  };

  cvt(x, xb, Mc * Dc);

  // QKV projections (V written directly in [b][h][d][s] transposed layout)
  cvt(Wq, wb, Dc * Dc);
  gemm256tb<0><<<dim3(32 * 8), dim3(512), 0, stream>>>(xb, wb, bq, qb, Mc, Dc, Dc);
  cvt(Wk, wb, Dc * Dc);
  gemm256tb<0><<<dim3(32 * 8), dim3(512), 0, stream>>>(xb, wb, bk, kb, Mc, Dc, Dc);
  cvt(Wv, wb, Dc * Dc);
  gemm256tb<2><<<dim3(32 * 8), dim3(512), 0, stream>>>(xb, wb, bv, vt, Mc, Dc, Dc);

  // mask bitmask (xb region is dead now)
  mask_bits<<<dim3(64), dim3(256), 0, stream>>>(mk, mbt);

  // attention
  attn_mfma<<<dim3(Bc * Hc * (Sc / 128)), dim3(256), 0, stream>>>(qb, kb, vt, mbt, ao);

  // output projection + LN1
  cvt(Wo, wb, Dc * Dc);
  gemm256tb<0><<<dim3(32 * 8), dim3(512), 0, stream>>>(ao, wb, bo, ap, Mc, Dc, Dc);
  ln_kernel<0, 1><<<dim3(Mc), dim3(256), 0, stream>>>(ap, x, g1, be1, x1);

  // FFN
  cvt(W1, wb, FFc * Dc);
  gemm256tb<1><<<dim3(32 * 32), dim3(512), 0, stream>>>(x1, wb, b1, hb, Mc, FFc, Dc);
  cvt(W2, wb, Dc * FFc);
  gemm256tb<0><<<dim3(32 * 8), dim3(512), 0, stream>>>(hb, wb, b2, ffn, Mc, Dc, FFc);
  ln_kernel<1, 0><<<dim3(Mc), dim3(256), 0, stream>>>(ffn, x1, g2, be2, outp);
}

// Round 7
// 1046.257 us; speedup vs baseline: 4.1292x; 1.1035x over previous
//
#include <hip/hip_runtime.h>
#include <cstdint>
#include <cstddef>

// ---------------------------------------------------------------------------
// EncoderLayer: B=8 S=1024 D=2048 H=16 Dh=128 FF=8192, fp32 in/out, bf16 compute
// ---------------------------------------------------------------------------

typedef unsigned short u16;
typedef unsigned int   u32;
typedef unsigned long long u64;
typedef __attribute__((ext_vector_type(8))) short short8;   // 8 x bf16 (4 VGPR)
typedef __attribute__((ext_vector_type(4))) float f32x4;

constexpr int Bc  = 8;
constexpr int Sc  = 1024;
constexpr int Dc  = 2048;
constexpr int Hc  = 16;
constexpr int Dhc = 128;
constexpr int FFc = 8192;
constexpr int Mc  = Bc * Sc;   // 8192 rows

// ---- bf16 helpers (manual, RNE) -------------------------------------------
__device__ __forceinline__ u16 f2b(float f) {
  u32 u = __builtin_bit_cast(u32, f);
  u += 0x7fffu + ((u >> 16) & 1u);
  return (u16)(u >> 16);
}
__device__ __forceinline__ u32 pack2(float a, float b) {
  return (u32)f2b(a) | ((u32)f2b(b) << 16);
}
__device__ __forceinline__ void unpack8(uint4 u, float* f) {
  u32 w[4] = {u.x, u.y, u.z, u.w};
#pragma unroll
  for (int i = 0; i < 4; ++i) {
    f[2 * i + 0] = __builtin_bit_cast(float, w[i] << 16);
    f[2 * i + 1] = __builtin_bit_cast(float, w[i] & 0xffff0000u);
  }
}

#define GLOAD_LDS16(gp, lp)                                                    \
  __builtin_amdgcn_global_load_lds(                                            \
      (const __attribute__((address_space(1))) void*)(gp),                     \
      (__attribute__((address_space(3))) void*)(lp), 16, 0, 0)

// ---- f32 -> bf16 conversion -----------------------------------------------
__global__ __launch_bounds__(256) void cvt_f32_bf16(const float* __restrict__ in,
                                                    u16* __restrict__ out, int n) {
  int i = (blockIdx.x * 256 + threadIdx.x) << 2;
  if (i >= n) return;
  float4 v = *(const float4*)(in + i);
  ushort4 o;
  o.x = f2b(v.x); o.y = f2b(v.y); o.z = f2b(v.z); o.w = f2b(v.w);
  *(ushort4*)(out + i) = o;
}

// ---- mask -> bitmask: mb[s][w] bit i = (mask[s][w*64+i] != 0) --------------
__global__ __launch_bounds__(256) void mask_bits(const int* __restrict__ mask,
                                                 u64* __restrict__ mb) {
  int t = blockIdx.x * 256 + threadIdx.x;   // 16384 = 1024 * 16
  int r = t >> 4, wd = t & 15;
  const int* p = mask + (size_t)r * Sc + wd * 64;
  u64 bits = 0;
#pragma unroll 16
  for (int i = 0; i < 64; i += 4) {
    int4 q = *(const int4*)(p + i);
    bits |= (u64)(q.x != 0) << (i + 0);
    bits |= (u64)(q.y != 0) << (i + 1);
    bits |= (u64)(q.z != 0) << (i + 2);
    bits |= (u64)(q.w != 0) << (i + 3);
  }
  mb[t] = bits;
}

// ---- 256x256 bf16 GEMM, register-prefetch pipeline -------------------------
// 8 waves (2Mx4N), BK=32, 4 LDS tile buffers (128 KB), st_16x32 swizzle.
// Iteration t: ISSUE ds_reads of tile t+1's frags (no wait) + ISSUE staging of
// tile t+3, then run 32 MFMA on tile t's frags (held in regs from last iter).
// Compiler emits counted lgkmcnt for the frag dependency -> next-tile LDS
// drain overlaps this tile's MFMA. ONE barrier per iteration.
// Hazard audit: (a) gload->ds_read same buffer: tile u staged at u-3, gated
// landed by vmcnt(4)-before-barrier at end of u-2 (per-wave own loads), read
// issued at u-1 after that barrier -> cross-wave safe. (b) ds_read->gload
// overwrite: reads of buf[u&3] (issued u-1) complete before each wave's MFMA
// in iter u (compiler wait), i.e. before end-of-u barrier; next write to that
// buffer (tile u+4) is issued in iter u+1 after that barrier. Tail: vmcnt(0)
// once staging stops (keeps round-5 race fix).
// MODE 0: bf16 out. MODE 1: ReLU + bf16 out. MODE 2: vt[b][h][d][s] write.
template <int MODE>
__global__ __launch_bounds__(512, 2) void gemm256tb(const u16* __restrict__ A,
                                                    const u16* __restrict__ Bt,
                                                    const float* __restrict__ bias,
                                                    u16* __restrict__ C,
                                                    int M, int N, int K) {
  __shared__ u16 Abuf[4][256 * 32];   // 64 KB
  __shared__ u16 Bbuf[4][256 * 32];   // 64 KB

  const int nbn = N >> 8;
  const int nwg = (M >> 8) * nbn;
  int bid = blockIdx.x;
  int sw = (bid & 7) * (nwg >> 3) + (bid >> 3);   // nwg multiple of 8 always
  const int m0 = (sw / nbn) << 8;
  const int n0 = (sw % nbn) << 8;

  const int tid  = threadIdx.x;
  const int lane = tid & 63;
  const int w    = tid >> 6;        // wave 0..7
  const int wm   = w >> 2;          // 0..1  (M half)
  const int wn   = w & 3;           // 0..3  (N quarter)

  const int rowA = lane & 15;
  const int g4   = lane >> 4;

  // Stage-source pre-swizzle (write side of st_16x32, inverse applied to the
  // per-lane global source so the LDS dest stays linear).
  const int p16  = lane << 4;
  const int wsw  = p16 ^ (((p16 >> 9) & 1) << 5);
  const int s_rr = wsw >> 6;            // row 0..15 within subtile
  const int s_cc = (wsw & 63) >> 1;     // col elem 0/8/16/24

  // ds_read swizzled byte offset within a 1024B subtile (read side)
  const int sb = (rowA * 64 + g4 * 16) ^ (((rowA >> 3) & 1) << 5);

  const int NT = K >> 5;   // K-tiles (64 or 256 here; always even, >= 8)

  const u16* Asrc = A  + (size_t)(m0 + w * 32 + s_rr) * K + s_cc;
  const u16* Bsrc = Bt + (size_t)(n0 + w * 32 + s_rr) * K + s_cc;

  // wave w stages subtiles 2w, 2w+1 (rows w*32 .. w*32+31) of a 256x32 tile
  auto stage = [&](int tt) {
    int buf = tt & 3;
#pragma unroll
    for (int i = 0; i < 2; ++i)
      GLOAD_LDS16(Asrc + (size_t)i * 16 * K + tt * 32, &Abuf[buf][(2 * w + i) * 512]);
#pragma unroll
    for (int i = 0; i < 2; ++i)
      GLOAD_LDS16(Bsrc + (size_t)i * 16 * K + tt * 32, &Bbuf[buf][(2 * w + i) * 512]);
  };

  auto readF = [&](int tt, short8* aF, short8* bF) {
    int buf = tt & 3;
#pragma unroll
    for (int n = 0; n < 4; ++n)
      bF[n] = *(const short8*)((const char*)&Bbuf[buf][(wn * 4 + n) * 512] + sb);
#pragma unroll
    for (int i = 0; i < 8; ++i)
      aF[i] = *(const short8*)((const char*)&Abuf[buf][(wm * 8 + i) * 512] + sb);
  };

  f32x4 acc[8][4];
#pragma unroll
  for (int m = 0; m < 8; ++m)
#pragma unroll
    for (int n = 0; n < 4; ++n) acc[m][n] = (f32x4){0.f, 0.f, 0.f, 0.f};

  // Prologue: stage tiles 0,1,2 (12 gloads); vmcnt(4) -> tiles 0,1 landed.
  stage(0); stage(1); stage(2);
  asm volatile("s_waitcnt vmcnt(4)" ::: "memory");
  __builtin_amdgcn_s_barrier();

  short8 a0[8], b0[4], a1[8], b1[4];
  readF(0, a0, b0);

  auto body = [&](int t, short8* aC, short8* bC, short8* aN, short8* bN) {
    if (t + 1 < NT) readF(t + 1, aN, bN);     // issue next-tile frag reads
    if (t + 3 < NT) stage(t + 3);             // issue next staging
    __builtin_amdgcn_sched_barrier(0);        // pin prefetch before MFMA
    __builtin_amdgcn_s_setprio(1);
#pragma unroll
    for (int i = 0; i < 8; ++i)
#pragma unroll
      for (int n = 0; n < 4; ++n)
        acc[i][n] = __builtin_amdgcn_mfma_f32_16x16x32_bf16(aC[i], bC[n], acc[i][n], 0, 0, 0);
    __builtin_amdgcn_s_setprio(0);
    if (t + 3 < NT) { asm volatile("s_waitcnt vmcnt(4)" ::: "memory"); }
    else            { asm volatile("s_waitcnt vmcnt(0)" ::: "memory"); }
    __builtin_amdgcn_s_barrier();
  };

  for (int t = 0; t < NT; t += 2) {
    body(t,     a0, b0, a1, b1);
    body(t + 1, a1, b1, a0, b0);
  }

  // ---- epilogue: C/D layout col=lane&15, row=(lane>>4)*4+j ------------------
  const int ci = lane & 15;
  const int ri = g4 << 2;
  float bvv[4];
#pragma unroll
  for (int n = 0; n < 4; ++n) bvv[n] = bias[n0 + wn * 64 + n * 16 + ci];

  if (MODE == 2) {
#pragma unroll
    for (int n = 0; n < 4; ++n) {
      int col = n0 + wn * 64 + n * 16 + ci;
#pragma unroll
      for (int m = 0; m < 8; ++m) {
        int row0 = m0 + wm * 128 + m * 16 + ri;
        ushort4 pk;
        pk.x = f2b(acc[m][n][0] + bvv[n]);
        pk.y = f2b(acc[m][n][1] + bvv[n]);
        pk.z = f2b(acc[m][n][2] + bvv[n]);
        pk.w = f2b(acc[m][n][3] + bvv[n]);
        size_t addr = ((size_t)((row0 >> 10) * Hc + (col >> 7)) * 128 + (col & 127)) * 1024
                      + (row0 & 1023);
        *(ushort4*)(C + addr) = pk;
      }
    }
  } else {
#pragma unroll
    for (int m = 0; m < 8; ++m) {
      int row0 = m0 + wm * 128 + m * 16 + ri;
#pragma unroll
      for (int j = 0; j < 4; ++j) {
        u16* cp = C + (size_t)(row0 + j) * N + n0 + wn * 64 + ci;
#pragma unroll
        for (int n = 0; n < 4; ++n) {
          float v = acc[m][n][j] + bvv[n];
          if (MODE == 1) v = fmaxf(v, 0.f);
          cp[n * 16] = f2b(v);
        }
      }
    }
  }
}

// ---- MFMA flash attention --------------------------------------------------
// Block: 256 thr (4 waves). QBLK=128 (wave owns 32 q-rows), KVBLK=64.
__global__ __launch_bounds__(256, 2) void attn_mfma(
    const u16* __restrict__ qb,   // [B*S][D]
    const u16* __restrict__ kb,   // [B*S][D]
    const u16* __restrict__ vt,   // [B*H][128][1024]   (d, s)
    const u64* __restrict__ mb,   // [S][16] bitmask
    u16* __restrict__ ob)         // [B*S][D]
{
  __shared__ u16 Ks[64 * 128];    // 16 KB, byte ^= ((krow&7)<<4), row stride 256B
  __shared__ u16 Vts[128 * 64];   // 16 KB, byte ^= ((drow&7)<<4), row stride 128B
  __shared__ u16 Ps[4][32 * 64];  // 16 KB, per-wave P, row stride 128B

  const int bid = blockIdx.x;
  const int l   = (bid & 7) * 128 + (bid >> 3);   // XCD-chunked
  const int qt  = l & 7;
  const int bh  = l >> 3;
  const int h   = bh & (Hc - 1);
  const int b   = bh >> 4;
  const int q0  = qt * 128;

  const int tid  = threadIdx.x;
  const int lane = tid & 63;
  const int w    = tid >> 6;
  const int rowA = lane & 15;
  const int g4   = lane >> 4;
  const int kq16 = g4 << 3;
  const int ri   = g4 << 2;

  const size_t tokbase = (size_t)b * Sc * Dc + (size_t)h * Dhc;
  const size_t vtbase  = (size_t)bh * 128 * 1024;
  const int qwbase = q0 + w * 32;

  short8 qf[2][4];
#pragma unroll
  for (int m = 0; m < 2; ++m)
#pragma unroll
    for (int kk = 0; kk < 4; ++kk)
      qf[m][kk] = *reinterpret_cast<const short8*>(
          qb + tokbase + (size_t)(qwbase + m * 16 + rowA) * Dc + kk * 32 + kq16);

  f32x4 O[2][8];
#pragma unroll
  for (int m = 0; m < 2; ++m)
#pragma unroll
    for (int n = 0; n < 8; ++n) O[m][n] = (f32x4){0.f, 0.f, 0.f, 0.f};
  float mrow[2][4], lrow[2][4];
#pragma unroll
  for (int m = 0; m < 2; ++m)
#pragma unroll
    for (int j = 0; j < 4; ++j) { mrow[m][j] = -INFINITY; lrow[m][j] = 0.f; }

  const float scale = 0.08838834764831845f;   // 1/sqrt(128)

  for (int kt = 0; kt < Sc / 64; ++kt) {
    const int k0 = kt * 64;
    __syncthreads();
#pragma unroll
    for (int i = 0; i < 4; ++i) {
      int chunk = w * 4 + i;
      int gb = (chunk * 64 + lane) * 16;
      int L  = gb ^ (((gb >> 8) & 7) << 4);
      int row = L >> 8, ce = (L & 255) >> 1;
      GLOAD_LDS16(kb + tokbase + (size_t)(k0 + row) * Dc + ce, &Ks[chunk * 512]);
    }
#pragma unroll
    for (int i = 0; i < 4; ++i) {
      int chunk = w * 4 + i;
      int gb = (chunk * 64 + lane) * 16;
      int L  = gb ^ (((gb >> 7) & 7) << 4);
      int row = L >> 7, ce = (L & 127) >> 1;
      GLOAD_LDS16(vt + vtbase + (size_t)row * 1024 + k0 + ce, &Vts[chunk * 512]);
    }
    __syncthreads();

    f32x4 s[2][4];
#pragma unroll
    for (int m = 0; m < 2; ++m)
#pragma unroll
      for (int n = 0; n < 4; ++n) s[m][n] = (f32x4){0.f, 0.f, 0.f, 0.f};
#pragma unroll
    for (int kk = 0; kk < 4; ++kk) {
      short8 bfk[4];
#pragma unroll
      for (int n = 0; n < 4; ++n) {
        int krow = n * 16 + rowA;
        int by = (krow * 256 + kk * 64 + (g4 << 4)) ^ ((krow & 7) << 4);
        bfk[n] = *reinterpret_cast<const short8*>((const char*)Ks + by);
      }
#pragma unroll
      for (int m = 0; m < 2; ++m)
#pragma unroll
        for (int n = 0; n < 4; ++n)
          s[m][n] = __builtin_amdgcn_mfma_f32_16x16x32_bf16(qf[m][kk], bfk[n], s[m][n], 0, 0, 0);
    }

    float alpha[2][4];
#pragma unroll
    for (int m = 0; m < 2; ++m) {
      u64 wb_[4];
#pragma unroll
      for (int j = 0; j < 4; ++j)
        wb_[j] = mb[(size_t)(qwbase + m * 16 + ri + j) * 16 + kt];
#pragma unroll
      for (int j = 0; j < 4; ++j) {
        float pv[4];
        float mx = -3.0e38f;
#pragma unroll
        for (int n = 0; n < 4; ++n) {
          float x = s[m][n][j] * scale;
          if (!((wb_[j] >> (n * 16 + rowA)) & 1)) x = -1e9f;
          pv[n] = x;
          mx = fmaxf(mx, x);
        }
        mx = fmaxf(mx, __shfl_xor(mx, 1));
        mx = fmaxf(mx, __shfl_xor(mx, 2));
        mx = fmaxf(mx, __shfl_xor(mx, 4));
        mx = fmaxf(mx, __shfl_xor(mx, 8));
        float mnew = fmaxf(mrow[m][j], mx);
        float a = __expf(mrow[m][j] - mnew);
        mrow[m][j] = mnew;
        alpha[m][j] = a;
        float rs = 0.f;
#pragma unroll
        for (int n = 0; n < 4; ++n) {
          float p = __expf(pv[n] - mnew);
          pv[n] = p;
          rs += p;
        }
        rs += __shfl_xor(rs, 1);
        rs += __shfl_xor(rs, 2);
        rs += __shfl_xor(rs, 4);
        rs += __shfl_xor(rs, 8);
        lrow[m][j] = lrow[m][j] * a + rs;
        int prow = m * 16 + ri + j;
#pragma unroll
        for (int n = 0; n < 4; ++n) {
          int by = (prow * 128 + 2 * (n * 16 + rowA)) ^ ((prow & 7) << 4);
          *(u16*)((char*)Ps[w] + by) = f2b(pv[n]);
        }
      }
    }
    asm volatile("s_waitcnt lgkmcnt(0)" ::: "memory");

#pragma unroll
    for (int m = 0; m < 2; ++m)
#pragma unroll
      for (int n = 0; n < 8; ++n)
#pragma unroll
        for (int j = 0; j < 4; ++j) O[m][n][j] *= alpha[m][j];

    short8 pa[2][2];
#pragma unroll
    for (int m = 0; m < 2; ++m)
#pragma unroll
      for (int kk = 0; kk < 2; ++kk) {
        int prow = m * 16 + rowA;
        int by = (prow * 128 + kk * 64 + (g4 << 4)) ^ ((prow & 7) << 4);
        pa[m][kk] = *reinterpret_cast<const short8*>((const char*)Ps[w] + by);
      }
#pragma unroll
    for (int kk = 0; kk < 2; ++kk)
#pragma unroll
      for (int n = 0; n < 8; ++n) {
        int drow = n * 16 + rowA;
        int by = (drow * 128 + kk * 64 + (g4 << 4)) ^ ((drow & 7) << 4);
        short8 bfv = *reinterpret_cast<const short8*>((const char*)Vts + by);
#pragma unroll
        for (int m = 0; m < 2; ++m)
          O[m][n] = __builtin_amdgcn_mfma_f32_16x16x32_bf16(pa[m][kk], bfv, O[m][n], 0, 0, 0);
      }
  }

  float inv[2][4];
#pragma unroll
  for (int m = 0; m < 2; ++m)
#pragma unroll
    for (int j = 0; j < 4; ++j) inv[m][j] = 1.f / lrow[m][j];
#pragma unroll
  for (int m = 0; m < 2; ++m)
#pragma unroll
    for (int n = 0; n < 8; ++n) {
      int dcol = n * 16 + rowA;
#pragma unroll
      for (int j = 0; j < 4; ++j) {
        int qg = qwbase + m * 16 + ri + j;
        ob[tokbase + (size_t)qg * Dc + dcol] = f2b(O[m][n][j] * inv[m][j]);
      }
    }
}

// ---- fused residual + LayerNorm -------------------------------------------
template <int RES_BF16, int OUT_BF16>
__global__ __launch_bounds__(256) void ln_kernel(const u16* __restrict__ a,
                                                 const void* __restrict__ resid,
                                                 const float* __restrict__ g,
                                                 const float* __restrict__ be,
                                                 void* __restrict__ out) {
  int row = blockIdx.x;
  int tid = threadIdx.x;
  int c0  = tid << 3;

  float v[8], vr[8];
  uint4 ua = *(const uint4*)(a + (size_t)row * Dc + c0);
  unpack8(ua, v);
  if (RES_BF16) {
    uint4 ur = *(const uint4*)((const u16*)resid + (size_t)row * Dc + c0);
    unpack8(ur, vr);
  } else {
    const float* rp = (const float*)resid + (size_t)row * Dc + c0;
    float4 f0 = *(const float4*)rp;
    float4 f1 = *(const float4*)(rp + 4);
    vr[0] = f0.x; vr[1] = f0.y; vr[2] = f0.z; vr[3] = f0.w;
    vr[4] = f1.x; vr[5] = f1.y; vr[6] = f1.z; vr[7] = f1.w;
  }

  float s = 0.f, ss = 0.f;
#pragma unroll
  for (int j = 0; j < 8; ++j) {
    v[j] += vr[j];
    s += v[j];
    ss += v[j] * v[j];
  }
#pragma unroll
  for (int off = 32; off; off >>= 1) {
    s  += __shfl_down(s, off);
    ss += __shfl_down(ss, off);
  }
  __shared__ float rs[4], rss[4], stat[2];
  if ((tid & 63) == 0) { rs[tid >> 6] = s; rss[tid >> 6] = ss; }
  __syncthreads();
  if (tid == 0) {
    float t  = rs[0] + rs[1] + rs[2] + rs[3];
    float tt = rss[0] + rss[1] + rss[2] + rss[3];
    float mean = t * (1.f / Dc);
    float var  = tt * (1.f / Dc) - mean * mean;
    stat[0] = mean;
    stat[1] = rsqrtf(var + 1e-5f);
  }
  __syncthreads();
  float mean = stat[0], rstd = stat[1];

  float y[8];
#pragma unroll
  for (int j = 0; j < 8; ++j) y[j] = (v[j] - mean) * rstd * g[c0 + j] + be[c0 + j];

  if (OUT_BF16) {
    uint4 o;
    o.x = pack2(y[0], y[1]); o.y = pack2(y[2], y[3]);
    o.z = pack2(y[4], y[5]); o.w = pack2(y[6], y[7]);
    *(uint4*)((u16*)out + (size_t)row * Dc + c0) = o;
  } else {
    float* op = (float*)out + (size_t)row * Dc + c0;
    *(float4*)op       = (float4){y[0], y[1], y[2], y[3]};
    *(float4*)(op + 4) = (float4){y[4], y[5], y[6], y[7]};
  }
}

// ---------------------------------------------------------------------------
extern "C" void kernel_launch(void* const* d_in, const int* in_sizes, int n_in,
                              void* d_out, int out_size, void* d_ws, size_t ws_size,
                              hipStream_t stream) {
  (void)in_sizes; (void)n_in; (void)out_size; (void)ws_size;

  const float* x   = (const float*)d_in[0];
  const int*   mk  = (const int*)d_in[1];
  const float* Wq  = (const float*)d_in[2];
  const float* bq  = (const float*)d_in[3];
  const float* Wk  = (const float*)d_in[4];
  const float* bk  = (const float*)d_in[5];
  const float* Wv  = (const float*)d_in[6];
  const float* bv  = (const float*)d_in[7];
  const float* Wo  = (const float*)d_in[8];
  const float* bo  = (const float*)d_in[9];
  const float* W1  = (const float*)d_in[10];
  const float* b1  = (const float*)d_in[11];
  const float* W2  = (const float*)d_in[12];
  const float* b2  = (const float*)d_in[13];
  const float* g1  = (const float*)d_in[14];
  const float* be1 = (const float*)d_in[15];
  const float* g2  = (const float*)d_in[16];
  const float* be2 = (const float*)d_in[17];
  float* outp = (float*)d_out;

  // workspace arena: 8 regions x 32MB (bf16, 16777216 elems each). Peak 256MB.
  const size_t R = 16777216;
  u16* xb  = (u16*)d_ws;       // [0] x bf16 (dead after V gemm)
  u16* wb  = xb + R;           // [1] weight staging (reused per GEMM)
  u16* qb  = wb + R;           // [2] q
  u16* kb  = qb + R;           // [3] k
  u16* vt  = kb + R;           // [4] V transposed [B][H][128][1024]
  u16* ao  = vt + R;           // [5] attention out (pre-Wo)
  u64* mbt = (u64*)d_ws;       // [0] mask bitmask (after xb dead), 128 KB
  u16* ap  = qb;               // [2] attn projection (q dead)
  u16* x1  = kb;               // [3] post-LN1 (k dead)
  u16* hb  = vt;               // [4..7] FFN hidden 8192x8192 (vt, ao dead)
  u16* ffn = xb;               // [0] FFN out

  auto cvt = [&](const float* src, u16* dst, int n) {
    cvt_f32_bf16<<<dim3((n + 1023) / 1024), dim3(256), 0, stream>>>(src, dst, n);
  };

  cvt(x, xb, Mc * Dc);

  // QKV projections (V written directly in [b][h][d][s] transposed layout)
  cvt(Wq, wb, Dc * Dc);
  gemm256tb<0><<<dim3(32 * 8), dim3(512), 0, stream>>>(xb, wb, bq, qb, Mc, Dc, Dc);
  cvt(Wk, wb, Dc * Dc);
  gemm256tb<0><<<dim3(32 * 8), dim3(512), 0, stream>>>(xb, wb, bk, kb, Mc, Dc, Dc);
  cvt(Wv, wb, Dc * Dc);
  gemm256tb<2><<<dim3(32 * 8), dim3(512), 0, stream>>>(xb, wb, bv, vt, Mc, Dc, Dc);

  // mask bitmask (xb region is dead now)
  mask_bits<<<dim3(64), dim3(256), 0, stream>>>(mk, mbt);

  // attention
  attn_mfma<<<dim3(Bc * Hc * (Sc / 128)), dim3(256), 0, stream>>>(qb, kb, vt, mbt, ao);

  // output projection + LN1
  cvt(Wo, wb, Dc * Dc);
  gemm256tb<0><<<dim3(32 * 8), dim3(512), 0, stream>>>(ao, wb, bo, ap, Mc, Dc, Dc);
  ln_kernel<0, 1><<<dim3(Mc), dim3(256), 0, stream>>>(ap, x, g1, be1, x1);

  // FFN
  cvt(W1, wb, FFc * Dc);
  gemm256tb<1><<<dim3(32 * 32), dim3(512), 0, stream>>>(x1, wb, b1, hb, Mc, FFc, Dc);
  cvt(W2, wb, Dc * FFc);
  gemm256tb<0><<<dim3(32 * 8), dim3(512), 0, stream>>>(hb, wb, b2, ffn, Mc, Dc, FFc);
  ln_kernel<1, 0><<<dim3(Mc), dim3(256), 0, stream>>>(ffn, x1, g2, be2, outp);
}